// Round 8
// baseline (809.836 us; speedup 1.0000x reference)
//
#include <hip/hip_runtime.h>
#include <hip/hip_bf16.h>
#include <cstddef>

// ---------------- problem constants ----------------
#define DMODEL  768
#define DINNER  1536
#define DSTATE  64
#define NH      24
#define HD      64
#define CONVD   1664      // DINNER + 2*DSTATE
#define DINPROJ 3224      // 2*DINNER + 2*DSTATE + NH
#define SEQ     4096
#define BSZ     2
#define NTOK    8192      // BSZ*SEQ
#define NCHUNK  64        // SEQ/64
#define EPSF    1e-5f
#define LP      72        // LDS pitch (shorts) for SSD kernels

typedef __attribute__((ext_vector_type(8))) short  short8;
typedef __attribute__((ext_vector_type(4))) float  f32x4;

// ---------------- helpers ----------------
__device__ __forceinline__ unsigned short f2bf(float f) {
  union { float f; unsigned int u; } v; v.f = f;
  unsigned int r = v.u + 0x7fffu + ((v.u >> 16) & 1u);   // RNE
  return (unsigned short)(r >> 16);
}
__device__ __forceinline__ float bf2f(unsigned short u) {
  union { unsigned int i; float f; } v; v.i = ((unsigned int)u) << 16; return v.f;
}
__device__ __forceinline__ unsigned long long pack4bf(float a, float b, float c, float d) {
  return (unsigned long long)(f2bf(a) | ((unsigned int)f2bf(b) << 16))
       | ((unsigned long long)(f2bf(c) | ((unsigned int)f2bf(d) << 16)) << 32);
}
__device__ __forceinline__ float sigm(float x) { return 1.f / (1.f + __expf(-x)); }

// async 16B global -> LDS (lane i of the wave lands at ldsbase + i*16)
__device__ __forceinline__ void gld16(const unsigned short* g, unsigned short* l) {
  __builtin_amdgcn_global_load_lds(
      (const __attribute__((address_space(1))) unsigned int*)g,
      (__attribute__((address_space(3))) unsigned int*)l, 16, 0, 0);
}

// ---------------- LayerNorm -> bf16 ----------------
__global__ __launch_bounds__(256) void k_ln(const float* __restrict__ x,
    const float* __restrict__ w, const float* __restrict__ b,
    unsigned short* __restrict__ xn)
{
  __shared__ float red[4];
  const int row = blockIdx.x, tid = threadIdx.x;
  const float* xr = x + (size_t)row * DMODEL;
  float v[3]; float s = 0.f;
  #pragma unroll
  for (int q = 0; q < 3; q++) { v[q] = xr[q*256 + tid]; s += v[q]; }
  #pragma unroll
  for (int off = 32; off; off >>= 1) s += __shfl_down(s, off);
  if ((tid & 63) == 0) red[tid >> 6] = s;
  __syncthreads();
  const float mu = (red[0] + red[1] + red[2] + red[3]) * (1.f / DMODEL);
  __syncthreads();
  float s2 = 0.f;
  #pragma unroll
  for (int q = 0; q < 3; q++) { float d = v[q] - mu; s2 += d * d; }
  #pragma unroll
  for (int off = 32; off; off >>= 1) s2 += __shfl_down(s2, off);
  if ((tid & 63) == 0) red[tid >> 6] = s2;
  __syncthreads();
  const float rs = rsqrtf((red[0] + red[1] + red[2] + red[3]) * (1.f / DMODEL) + EPSF);
  unsigned short* xo = xn + (size_t)row * DMODEL;
  #pragma unroll
  for (int q = 0; q < 3; q++) {
    int col = q*256 + tid;
    xo[col] = f2bf((v[q] - mu) * rs * w[col] + b[col]);
  }
}

// ---------------- 4 weight transposes in one dispatch (z-indexed) ----------------
__global__ __launch_bounds__(256) void k_wtrans4(
    const float* __restrict__ W0, unsigned short* __restrict__ T0,
    const float* __restrict__ W1, unsigned short* __restrict__ T1,
    const float* __restrict__ W2, unsigned short* __restrict__ T2,
    const float* __restrict__ W3, unsigned short* __restrict__ T3)
{
  const float* W; unsigned short* T; int K, N;
  switch (blockIdx.z) {
    case 0:  W = W0; T = T0; K = 768;  N = 3224; break;
    case 1:  W = W1; T = T1; K = 768;  N = 768;  break;
    case 2:  W = W2; T = T2; K = 1536; N = 768;  break;
    default: W = W3; T = T3; K = 768;  N = 768;  break;
  }
  const int n0 = blockIdx.x * 32, k0 = blockIdx.y * 32;
  if (n0 >= N || k0 >= K) return;
  __shared__ float tile[32][33];
  const int tid = threadIdx.x;
  const int tx = tid & 31, ty = tid >> 5;           // 32 x 8
  #pragma unroll
  for (int r = 0; r < 4; r++) {
    int k = k0 + ty + 8*r;
    if (k < K && n0 + tx < N) tile[ty + 8*r][tx] = W[(size_t)k * N + n0 + tx];
  }
  __syncthreads();
  #pragma unroll
  for (int r = 0; r < 4; r++) {
    int n = n0 + ty + 8*r, k = k0 + tx;
    if (n < N && k < K) T[(size_t)n * K + k] = f2bf(tile[tx][ty + 8*r]);
  }
}

// ======== 128x128 GEMM core: C[M][N] = A[M][K] @ Bt[N][K]^T, BK=64 ===============
// LDS swizzle: slot j of row r holds k-granule g = j ^ (r&7)  (granule = 16B).
// epi: 0 plain, 1 sigmoid(C+bias[n]), 2 C+bias[n]+resid[m][n].  Cb!=null -> bf16 out.
__device__ __forceinline__ void gemm_core(const unsigned short* __restrict__ A,
    const unsigned short* __restrict__ Bt, float* __restrict__ C,
    unsigned short* __restrict__ Cb,
    int M, int N, int K, int epi, const float* __restrict__ bias,
    const float* __restrict__ resid, int m0, int n0,
    unsigned short* As, unsigned short* Bs)
{
  const int tid = threadIdx.x;
  const int lane = tid & 63, w = tid >> 6;
  const int wm = (w >> 1) * 64, wn = (w & 1) * 64;
  const int l15 = lane & 15, lq = lane >> 4;
  const int sw = l15 & 7;                  // fragment-read swizzle
  f32x4 acc[4][4];
  #pragma unroll
  for (int i = 0; i < 4; i++)
    #pragma unroll
    for (int j = 0; j < 4; j++) acc[i][j] = (f32x4){0.f, 0.f, 0.f, 0.f};

  int rowg[4], gq[4];
  #pragma unroll
  for (int r = 0; r < 4; r++) {
    int gi = (r * 4 + w) * 64 + lane;
    rowg[r] = gi >> 3;
    gq[r] = (gi & 7) ^ (rowg[r] & 7);
  }

  for (int k0 = 0; k0 < K; k0 += 64) {
    __syncthreads();
    #pragma unroll
    for (int r = 0; r < 4; r++)
      gld16(A + (size_t)(m0 + rowg[r]) * K + k0 + gq[r] * 8, &As[(r * 4 + w) * 512]);
    #pragma unroll
    for (int r = 0; r < 4; r++) {
      int nr = n0 + rowg[r]; if (nr >= N) nr = N - 1;   // clamp; cols >= N masked in epilogue
      gld16(Bt + (size_t)nr * K + k0 + gq[r] * 8, &Bs[(r * 4 + w) * 512]);
    }
    __syncthreads();
    #pragma unroll
    for (int ks = 0; ks < 2; ks++) {
      short8 a8[4], b8[4];
      #pragma unroll
      for (int mi = 0; mi < 4; mi++)
        a8[mi] = *(const short8*)(&As[(wm + 16 * mi + l15) * 64 + ((lq + 4 * ks) ^ sw) * 8]);
      #pragma unroll
      for (int ni = 0; ni < 4; ni++)
        b8[ni] = *(const short8*)(&Bs[(wn + 16 * ni + l15) * 64 + ((lq + 4 * ks) ^ sw) * 8]);
      #pragma unroll
      for (int mi = 0; mi < 4; mi++)
        #pragma unroll
        for (int ni = 0; ni < 4; ni++)
          acc[mi][ni] = __builtin_amdgcn_mfma_f32_16x16x32_bf16(a8[mi], b8[ni], acc[mi][ni], 0, 0, 0);
    }
  }
  #pragma unroll
  for (int mi = 0; mi < 4; mi++) {
    #pragma unroll
    for (int r = 0; r < 4; r++) {
      int row = m0 + wm + 16*mi + lq*4 + r;
      #pragma unroll
      for (int ni = 0; ni < 4; ni++) {
        int col = n0 + wn + 16*ni + l15;
        if (col < N) {
          float vv = acc[mi][ni][r];
          if (epi == 1)      vv = sigm(vv + bias[col]);
          else if (epi == 2) vv = vv + bias[col] + resid[(size_t)row * N + col];
          if (Cb) Cb[(size_t)row * N + col] = f2bf(vv);
          else    C [(size_t)row * N + col] = vv;
        }
      }
    }
  }
}

__global__ __launch_bounds__(256) void k_gemm(const unsigned short* __restrict__ A,
    const unsigned short* __restrict__ Bt, float* __restrict__ C,
    unsigned short* __restrict__ Cb,
    int M, int N, int K, int epi, const float* __restrict__ bias,
    const float* __restrict__ resid)
{
  __shared__ alignas(16) unsigned short As[128 * 64];
  __shared__ alignas(16) unsigned short Bs[128 * 64];
  gemm_core(A, Bt, C, Cb, M, N, K, epi, bias, resid,
            blockIdx.y * 128, blockIdx.x * 128, As, Bs);
}

// two independent bf16-out GEMMs in one dispatch (z-plane):
// z=0: out_proj  YN @ WOPT -> YPb (K=1536)    z=1: gate XN @ WGT -> Gb (K=768, sigmoid)
__global__ __launch_bounds__(256) void k_dualgemm(
    const unsigned short* __restrict__ A0, const unsigned short* __restrict__ B0,
    unsigned short* __restrict__ C0, int K0,
    const unsigned short* __restrict__ A1, const unsigned short* __restrict__ B1,
    unsigned short* __restrict__ C1, int K1, const float* __restrict__ bias1, int N)
{
  __shared__ alignas(16) unsigned short As[128 * 64];
  __shared__ alignas(16) unsigned short Bs[128 * 64];
  if (blockIdx.z == 0)
    gemm_core(A0, B0, nullptr, C0, NTOK, N, K0, 0, nullptr, nullptr,
              blockIdx.y * 128, blockIdx.x * 128, As, Bs);
  else
    gemm_core(A1, B1, nullptr, C1, NTOK, N, K1, 1, bias1, nullptr,
              blockIdx.y * 128, blockIdx.x * 128, As, Bs);
}

// ---------------- SSD pass 1 (MFMA), conv fused in staging -----------------------
// S[bh,c][n][p] = sum_s (Bconv[s][n]*wv[s]) Xconv[s][p]
__global__ __launch_bounds__(256) void k_chunkstate(const unsigned short* __restrict__ zx,
    const float* __restrict__ cw, const float* __restrict__ cb,
    const float* __restrict__ dt_bias, const float* __restrict__ A_log,
    float* __restrict__ S, float* __restrict__ CD)
{
  const int c = blockIdx.x, bh = blockIdx.y;
  const int b = bh / NH, h = bh % NH;
  const int tid = threadIdx.x;
  const int lane = tid & 63, w = tid >> 6;
  const int l15 = lane & 15, lq = lane >> 4;
  __shared__ float wv_[64];
  __shared__ alignas(16) unsigned short Bwt[64][LP];  // [n][s]
  __shared__ alignas(16) unsigned short Xt [64][LP];  // [p][s]

  if (tid < 64) {                     // wave 0: dt, prefix-scan of Lc
    int t = c * 64 + tid;
    float xx = bf2f(zx[((size_t)(b * SEQ + t)) * DINPROJ + (DINNER + CONVD) + h]) + dt_bias[h];
    float dt_ = (xx > 15.f) ? xx : log1pf(__expf(xx));
    float Ah = -__expf(A_log[h]);
    float v = dt_ * Ah;
    #pragma unroll
    for (int off = 1; off < 64; off <<= 1) {
      float u = __shfl_up(v, off);
      if (tid >= off) v += u;
    }
    float L63 = __shfl(v, 63);
    wv_[tid] = __expf(L63 - v) * dt_;
    if (tid == 63) CD[bh * 64 + c] = __expf(v);
  }
  const int t0 = c * 64;
  float bk[4][4];                     // conv'd B (silu), kept until wv_ is ready
  #pragma unroll
  for (int it = 0; it < 4; it++) {
    int i4 = tid + 256 * it;
    int rr = i4 >> 4, q4 = (i4 & 15) * 4;
    float4 cbB = *(const float4*)(cb + DINNER + q4);
    float4 cbX = *(const float4*)(cb + h * HD + q4);
    float aB[4] = {cbB.x, cbB.y, cbB.z, cbB.w};
    float aX[4] = {cbX.x, cbX.y, cbX.z, cbX.w};
    #pragma unroll
    for (int k = 0; k < 4; k++) {
      int t = t0 + rr - 3 + k;
      if (t >= 0) {
        const unsigned short* rp = zx + ((size_t)b * SEQ + t) * DINPROJ;
        unsigned short ub[4], ux[4];
        *(unsigned long long*)ub = *(const unsigned long long*)(rp + 2 * DINNER + q4);
        *(unsigned long long*)ux = *(const unsigned long long*)(rp + DINNER + h * HD + q4);
        #pragma unroll
        for (int j = 0; j < 4; j++) {
          aB[j] += bf2f(ub[j]) * cw[(DINNER + q4 + j) * 4 + k];
          aX[j] += bf2f(ux[j]) * cw[(h * HD + q4 + j) * 4 + k];
        }
      }
    }
    #pragma unroll
    for (int j = 0; j < 4; j++) {
      bk[it][j] = aB[j] * sigm(aB[j]);
      float xs = aX[j] * sigm(aX[j]);
      Xt[q4 + j][rr] = f2bf(xs);
    }
  }
  __syncthreads();                    // wv_ ready
  #pragma unroll
  for (int it = 0; it < 4; it++) {
    int i4 = tid + 256 * it;
    int rr = i4 >> 4, q4 = (i4 & 15) * 4;
    float wsc = wv_[rr];
    #pragma unroll
    for (int j = 0; j < 4; j++) Bwt[q4 + j][rr] = f2bf(bk[it][j] * wsc);
  }
  __syncthreads();
  const int n0 = 16 * w;
  short8 a0 = *(const short8*)(&Bwt[n0 + l15][lq * 8]);
  short8 a1 = *(const short8*)(&Bwt[n0 + l15][32 + lq * 8]);
  size_t sb = ((size_t)bh * 64 + c) * 4096;
  #pragma unroll
  for (int pt = 0; pt < 4; pt++) {
    f32x4 acc = (f32x4){0.f, 0.f, 0.f, 0.f};
    short8 b0 = *(const short8*)(&Xt[16*pt + l15][lq * 8]);
    short8 b1 = *(const short8*)(&Xt[16*pt + l15][32 + lq * 8]);
    acc = __builtin_amdgcn_mfma_f32_16x16x32_bf16(a0, b0, acc, 0, 0, 0);
    acc = __builtin_amdgcn_mfma_f32_16x16x32_bf16(a1, b1, acc, 0, 0, 0);
    #pragma unroll
    for (int r = 0; r < 4; r++) {
      int n = n0 + 4*lq + r, p = 16*pt + l15;
      S[sb + (size_t)n * 64 + p] = acc[r];
    }
  }
}

// ---------------- SSD pass 2: chunk-level recurrence (in-place S -> G) -----------
__global__ __launch_bounds__(256) void k_chunkrec(float* __restrict__ S,
    const float* __restrict__ CD)
{
  const int bh = blockIdx.x >> 4, part = blockIdx.x & 15;
  const int e = part * 256 + threadIdx.x;
  float g = 0.f;
  size_t base = (size_t)bh * 64 * 4096 + e;
  for (int c = 0; c < 64; c++) {
    size_t ad = base + (size_t)c * 4096;
    float sv = S[ad];
    float pc = CD[bh * 64 + c];
    S[ad] = g;               // slot c now holds G_c (state before chunk c)
    g = pc * g + sv;
  }
}

// ---------------- SSD pass 3 (MFMA), conv fused in staging (bf16 Y out) ----------
__global__ __launch_bounds__(256) void k_chunkout(const unsigned short* __restrict__ zx,
    const float* __restrict__ cw, const float* __restrict__ cb,
    const float* __restrict__ S, const float* __restrict__ dt_bias,
    const float* __restrict__ A_log, const float* __restrict__ Dp,
    unsigned short* __restrict__ Y)
{
  const int c = blockIdx.x, bh = blockIdx.y;
  const int b = bh / NH, h = bh % NH;
  const int tid = threadIdx.x;
  const int lane = tid & 63, w = tid >> 6;
  const int l15 = lane & 15, lq = lane >> 4;
  __shared__ float dts[64], Lc[64], ein[64];
  __shared__ alignas(16) unsigned short Cs  [64][LP];  // [i][n]
  __shared__ alignas(16) unsigned short BsPs[64][LP];  // [s][n], then P[i][s]
  __shared__ alignas(16) unsigned short Xt  [64][LP];  // [p][s]
  __shared__ alignas(16) unsigned short Gt  [64][LP];  // [p][n]

  if (tid < 64) {                     // wave 0: dt, prefix-scan of Lc
    int t = c * 64 + tid;
    float xx = bf2f(zx[((size_t)(b * SEQ + t)) * DINPROJ + (DINNER + CONVD) + h]) + dt_bias[h];
    float dt_ = (xx > 15.f) ? xx : log1pf(__expf(xx));
    dts[tid] = dt_;
    float Ah = -__expf(A_log[h]);
    float v = dt_ * Ah;
    #pragma unroll
    for (int off = 1; off < 64; off <<= 1) {
      float u = __shfl_up(v, off);
      if (tid >= off) v += u;
    }
    Lc[tid] = v;
    ein[tid] = __expf(v);
  }
  const int t0 = c * 64;
  const size_t gslot = ((size_t)bh * 64 + c) * 4096;
  #pragma unroll
  for (int it = 0; it < 4; it++) {
    int i4 = tid + 256 * it;
    int rr = i4 >> 4, q4 = (i4 & 15) * 4;
    float4 cbC = *(const float4*)(cb + DINNER + DSTATE + q4);
    float4 cbB = *(const float4*)(cb + DINNER + q4);
    float4 cbX = *(const float4*)(cb + h * HD + q4);
    float aC[4] = {cbC.x, cbC.y, cbC.z, cbC.w};
    float aB[4] = {cbB.x, cbB.y, cbB.z, cbB.w};
    float aX[4] = {cbX.x, cbX.y, cbX.z, cbX.w};
    #pragma unroll
    for (int k = 0; k < 4; k++) {
      int t = t0 + rr - 3 + k;
      if (t >= 0) {
        const unsigned short* rp = zx + ((size_t)b * SEQ + t) * DINPROJ;
        unsigned short uc[4], ub[4], ux[4];
        *(unsigned long long*)uc = *(const unsigned long long*)(rp + 2 * DINNER + DSTATE + q4);
        *(unsigned long long*)ub = *(const unsigned long long*)(rp + 2 * DINNER + q4);
        *(unsigned long long*)ux = *(const unsigned long long*)(rp + DINNER + h * HD + q4);
        #pragma unroll
        for (int j = 0; j < 4; j++) {
          aC[j] += bf2f(uc[j]) * cw[(DINNER + DSTATE + q4 + j) * 4 + k];
          aB[j] += bf2f(ub[j]) * cw[(DINNER + q4 + j) * 4 + k];
          aX[j] += bf2f(ux[j]) * cw[(h * HD + q4 + j) * 4 + k];
        }
      }
    }
    float sC[4], sB[4];
    #pragma unroll
    for (int j = 0; j < 4; j++) {
      sC[j] = aC[j] * sigm(aC[j]);
      sB[j] = aB[j] * sigm(aB[j]);
      float xs = aX[j] * sigm(aX[j]);
      Xt[q4 + j][rr] = f2bf(xs);
    }
    *(unsigned long long*)(&Cs[rr][q4])   = pack4bf(sC[0], sC[1], sC[2], sC[3]);
    *(unsigned long long*)(&BsPs[rr][q4]) = pack4bf(sB[0], sB[1], sB[2], sB[3]);
    float4 vG = *(const float4*)(S + gslot + (size_t)i4 * 4);   // row n=rr, cols q4..q4+3
    Gt[q4+0][rr] = f2bf(vG.x); Gt[q4+1][rr] = f2bf(vG.y);
    Gt[q4+2][rr] = f2bf(vG.z); Gt[q4+3][rr] = f2bf(vG.w);
  }
  __syncthreads();
  // ---- matmul1: G[i][s] = sum_n C[i][n] B[s][n]; apply causal decay mask -> P ----
  const int i0 = 16 * w;
  short8 ac0 = *(const short8*)(&Cs[i0 + l15][lq * 8]);
  short8 ac1 = *(const short8*)(&Cs[i0 + l15][32 + lq * 8]);
  float pp[4][4];
  #pragma unroll
  for (int st = 0; st < 4; st++) {
    f32x4 g = (f32x4){0.f, 0.f, 0.f, 0.f};
    if (st <= w) {                                   // wave-uniform causal skip
      short8 b0 = *(const short8*)(&BsPs[16*st + l15][lq * 8]);
      short8 b1 = *(const short8*)(&BsPs[16*st + l15][32 + lq * 8]);
      g = __builtin_amdgcn_mfma_f32_16x16x32_bf16(ac0, b0, g, 0, 0, 0);
      g = __builtin_amdgcn_mfma_f32_16x16x32_bf16(ac1, b1, g, 0, 0, 0);
    }
    #pragma unroll
    for (int r = 0; r < 4; r++) {
      int i = i0 + 4*lq + r, s = 16*st + l15;
      pp[st][r] = (s <= i) ? g[r] * __expf(Lc[i] - Lc[s]) * dts[s] : 0.f;
    }
  }
  __syncthreads();                                   // all waves done reading Bs
  #pragma unroll
  for (int st = 0; st < 4; st++)
    #pragma unroll
    for (int r = 0; r < 4; r++)
      BsPs[i0 + 4*lq + r][16*st + l15] = f2bf(pp[st][r]);   // P[i][s], s contiguous
  __syncthreads();
  // ---- matmul2+3: Y[i][p] = P@X + ein[i]*(C@G) + D*x ----
  short8 ap0 = *(const short8*)(&BsPs[i0 + l15][lq * 8]);
  short8 ap1 = *(const short8*)(&BsPs[i0 + l15][32 + lq * 8]);
  const float Dh = Dp[h];
  #pragma unroll
  for (int pt = 0; pt < 4; pt++) {
    const int p0 = 16 * pt;
    f32x4 y1 = (f32x4){0.f, 0.f, 0.f, 0.f};
    f32x4 y2 = (f32x4){0.f, 0.f, 0.f, 0.f};
    short8 bx0 = *(const short8*)(&Xt[p0 + l15][lq * 8]);
    y1 = __builtin_amdgcn_mfma_f32_16x16x32_bf16(ap0, bx0, y1, 0, 0, 0);
    if (w >= 2) {                                    // P rows of wave w have k < 16(w+1)
      short8 bx1 = *(const short8*)(&Xt[p0 + l15][32 + lq * 8]);
      y1 = __builtin_amdgcn_mfma_f32_16x16x32_bf16(ap1, bx1, y1, 0, 0, 0);
    }
    short8 bg0 = *(const short8*)(&Gt[p0 + l15][lq * 8]);
    short8 bg1 = *(const short8*)(&Gt[p0 + l15][32 + lq * 8]);
    y2 = __builtin_amdgcn_mfma_f32_16x16x32_bf16(ac0, bg0, y2, 0, 0, 0);
    y2 = __builtin_amdgcn_mfma_f32_16x16x32_bf16(ac1, bg1, y2, 0, 0, 0);
    #pragma unroll
    for (int r = 0; r < 4; r++) {
      int i = i0 + 4*lq + r, p = p0 + l15;
      float xv = bf2f(Xt[p][i]);
      float o = y1[r] + ein[i] * y2[r] + Dh * xv;
      Y[((size_t)(b * SEQ) + c * 64 + i) * DINNER + h * HD + p] = f2bf(o);
    }
  }
}

// ---------------- y*silu(z), RMSNorm -> bf16 -------------------------------------
__global__ __launch_bounds__(256) void k_fuse(const unsigned short* __restrict__ Y,
    const unsigned short* __restrict__ ZX, const float* __restrict__ rw,
    unsigned short* __restrict__ YN)
{
  __shared__ float red[4];
  const int row = blockIdx.x, tid = threadIdx.x;
  const unsigned short* yr = Y + (size_t)row * DINNER;
  const unsigned short* zr = ZX + (size_t)row * DINPROJ;
  float v[6]; float s2 = 0.f;
  #pragma unroll
  for (int q = 0; q < 6; q++) {
    int col = q * 256 + tid;
    float z = bf2f(zr[col]);
    float yv = bf2f(yr[col]) * (z * sigm(z));
    v[q] = yv; s2 += yv * yv;
  }
  #pragma unroll
  for (int off = 32; off; off >>= 1) s2 += __shfl_down(s2, off);
  if ((tid & 63) == 0) red[tid >> 6] = s2;
  __syncthreads();
  const float rs = rsqrtf((red[0] + red[1] + red[2] + red[3]) * (1.f / DINNER) + EPSF);
  unsigned short* yo = YN + (size_t)row * DINNER;
  #pragma unroll
  for (int q = 0; q < 6; q++) {
    int col = q * 256 + tid;
    yo[col] = f2bf(v[q] * rs * rw[col]);
  }
}

// ---------------- yg = bf16(yproj * gate), 4 elems/thread ------------------------
__global__ __launch_bounds__(256) void k_gatemul(const unsigned short* __restrict__ YP,
    const unsigned short* __restrict__ G, unsigned short* __restrict__ YG)
{
  size_t i4 = ((size_t)blockIdx.x * 256 + threadIdx.x) * 4;
  unsigned short a[4], b[4];
  *(unsigned long long*)a = *(const unsigned long long*)(YP + i4);
  *(unsigned long long*)b = *(const unsigned long long*)(G + i4);
  *(unsigned long long*)(YG + i4) = pack4bf(
      bf2f(a[0]) * bf2f(b[0]), bf2f(a[1]) * bf2f(b[1]),
      bf2f(a[2]) * bf2f(b[2]), bf2f(a[3]) * bf2f(b[3]));
}

// ---------------- launch ----------------------------------------------------------
extern "C" void kernel_launch(void* const* d_in, const int* in_sizes, int n_in,
                              void* d_out, int out_size, void* d_ws, size_t ws_size,
                              hipStream_t stream)
{
  const float* x         = (const float*)d_in[0];
  const float* ln_w      = (const float*)d_in[1];
  const float* ln_b      = (const float*)d_in[2];
  const float* in_proj_w = (const float*)d_in[3];
  const float* conv_w    = (const float*)d_in[4];
  const float* conv_b    = (const float*)d_in[5];
  const float* dt_bias   = (const float*)d_in[6];
  const float* A_log     = (const float*)d_in[7];
  const float* D_param   = (const float*)d_in[8];
  const float* rms_w     = (const float*)d_in[9];
  const float* out_proj_w= (const float*)d_in[10];
  const float* gate_w    = (const float*)d_in[11];
  const float* gate_b    = (const float*)d_in[12];
  const float* out_w     = (const float*)d_in[13];
  const float* out_b     = (const float*)d_in[14];
  float* out = (float*)d_out;
  char* ws = (char*)d_ws;

  // ---- workspace layout (bytes). peak = 177,848,320 B (~170 MB) ----
  const size_t WS_NEEDED = 177848320ull;
  if (ws_size < WS_NEEDED) return;

  unsigned short* XN    = (unsigned short*)(ws + 0);
  unsigned short* WIT   = (unsigned short*)(ws + 12582912);
  unsigned short* WGT   = (unsigned short*)(ws + 17534976);
  unsigned short* WOPT  = (unsigned short*)(ws + 18714624);
  unsigned short* WOT   = (unsigned short*)(ws + 21073920);
  unsigned short* ZXb   = (unsigned short*)(ws + 22253568);   // 8192x3224 bf16
  float*          SG    = (float*)(ws + 102338560);           // 3072x4096 f32
  float*          CD    = (float*)(ws + 152670208);           // 3072 f32
  unsigned short* Yb    = (unsigned short*)(ws + 152682496);  // 8192x1536 bf16
  // overlays:
  unsigned short* YN    = (unsigned short*)(ws + 102338560);  // in SG region (dead after chunkout)
  unsigned short* Gb    = (unsigned short*)(ws + 22253568);   // in ZXb region (dead after fuse)
  unsigned short* YPb   = (unsigned short*)(ws + 34836480);   // in ZXb region
  unsigned short* YG    = (unsigned short*)(ws + 75075584);   // former XBCCb region (unused now)

  // 1) weight converts, single dispatch
  k_wtrans4<<<dim3(101, 48, 4), 256, 0, stream>>>(in_proj_w, WIT, gate_w, WGT,
                                                  out_proj_w, WOPT, out_w, WOT);
  // 2) layernorm
  k_ln<<<NTOK, 256, 0, stream>>>(x, ln_w, ln_b, XN);
  // 3) in_proj GEMM -> zxbcdt (bf16), proven 128x128 config
  k_gemm<<<dim3(26, 64), 256, 0, stream>>>(XN, WIT, nullptr, ZXb, NTOK, DINPROJ, DMODEL, 0, nullptr, nullptr);
  // 4-6) SSD scan (conv+SiLU fused into staging of both chunk kernels)
  k_chunkstate<<<dim3(NCHUNK, BSZ * NH), 256, 0, stream>>>(ZXb, conv_w, conv_b, dt_bias, A_log, SG, CD);
  k_chunkrec<<<BSZ * NH * 16, 256, 0, stream>>>(SG, CD);
  k_chunkout<<<dim3(NCHUNK, BSZ * NH), 256, 0, stream>>>(ZXb, conv_w, conv_b, SG, dt_bias, A_log, D_param, Yb);
  // 7) y*silu(z) + RMSNorm -> bf16 (YN lands in dead SG region)
  k_fuse<<<NTOK, 256, 0, stream>>>(Yb, ZXb, rms_w, YN);
  // 8+9) gate GEMM (sigmoid) + out_proj GEMM, one dispatch, bf16 outputs
  k_dualgemm<<<dim3(6, 64, 2), 256, 0, stream>>>(YN, WOPT, YPb, DINNER,
                                                 XN, WGT, Gb, DMODEL, gate_b, DMODEL);
  // 10) gate multiply -> bf16
  k_gatemul<<<(NTOK * DMODEL / 4) / 256, 256, 0, stream>>>(YPb, Gb, YG);
  // 11) final GEMM + bias + residual -> d_out
  k_gemm<<<dim3(6, 64), 256, 0, stream>>>(YG, WOT, out, nullptr, NTOK, DMODEL, DMODEL, 2, out_b, x);
}

// Round 9
// 417.985 us; speedup vs baseline: 1.9375x; 1.9375x over previous
//
#include <hip/hip_runtime.h>
#include <hip/hip_bf16.h>
#include <cstddef>

// ---------------- problem constants ----------------
#define DMODEL  768
#define DINNER  1536
#define DSTATE  64
#define NH      24
#define HD      64
#define CONVD   1664      // DINNER + 2*DSTATE
#define DINPROJ 3224      // 2*DINNER + 2*DSTATE + NH
#define SEQ     4096
#define BSZ     2
#define NTOK    8192      // BSZ*SEQ
#define NCHUNK  64        // SEQ/64
#define EPSF    1e-5f
#define LP      72        // LDS pitch (shorts) for SSD kernels

typedef __attribute__((ext_vector_type(8))) short  short8;
typedef __attribute__((ext_vector_type(4))) float  f32x4;

// ---------------- helpers ----------------
__device__ __forceinline__ unsigned short f2bf(float f) {
  union { float f; unsigned int u; } v; v.f = f;
  unsigned int r = v.u + 0x7fffu + ((v.u >> 16) & 1u);   // RNE
  return (unsigned short)(r >> 16);
}
__device__ __forceinline__ float bf2f(unsigned short u) {
  union { unsigned int i; float f; } v; v.i = ((unsigned int)u) << 16; return v.f;
}
__device__ __forceinline__ unsigned long long pack4bf(float a, float b, float c, float d) {
  return (unsigned long long)(f2bf(a) | ((unsigned int)f2bf(b) << 16))
       | ((unsigned long long)(f2bf(c) | ((unsigned int)f2bf(d) << 16)) << 32);
}
__device__ __forceinline__ float sigm(float x) { return 1.f / (1.f + __expf(-x)); }

// async 16B global -> LDS (lane i of the wave lands at ldsbase + i*16)
__device__ __forceinline__ void gld16(const unsigned short* g, unsigned short* l) {
  __builtin_amdgcn_global_load_lds(
      (const __attribute__((address_space(1))) unsigned int*)g,
      (__attribute__((address_space(3))) unsigned int*)l, 16, 0, 0);
}

// ---------------- LayerNorm -> bf16 ----------------
__global__ __launch_bounds__(256) void k_ln(const float* __restrict__ x,
    const float* __restrict__ w, const float* __restrict__ b,
    unsigned short* __restrict__ xn)
{
  __shared__ float red[4];
  const int row = blockIdx.x, tid = threadIdx.x;
  const float* xr = x + (size_t)row * DMODEL;
  float v[3]; float s = 0.f;
  #pragma unroll
  for (int q = 0; q < 3; q++) { v[q] = xr[q*256 + tid]; s += v[q]; }
  #pragma unroll
  for (int off = 32; off; off >>= 1) s += __shfl_down(s, off);
  if ((tid & 63) == 0) red[tid >> 6] = s;
  __syncthreads();
  const float mu = (red[0] + red[1] + red[2] + red[3]) * (1.f / DMODEL);
  __syncthreads();
  float s2 = 0.f;
  #pragma unroll
  for (int q = 0; q < 3; q++) { float d = v[q] - mu; s2 += d * d; }
  #pragma unroll
  for (int off = 32; off; off >>= 1) s2 += __shfl_down(s2, off);
  if ((tid & 63) == 0) red[tid >> 6] = s2;
  __syncthreads();
  const float rs = rsqrtf((red[0] + red[1] + red[2] + red[3]) * (1.f / DMODEL) + EPSF);
  unsigned short* xo = xn + (size_t)row * DMODEL;
  #pragma unroll
  for (int q = 0; q < 3; q++) {
    int col = q*256 + tid;
    xo[col] = f2bf((v[q] - mu) * rs * w[col] + b[col]);
  }
}

// ---------------- 4 weight transposes in one dispatch (z-indexed) ----------------
__global__ __launch_bounds__(256) void k_wtrans4(
    const float* __restrict__ W0, unsigned short* __restrict__ T0,
    const float* __restrict__ W1, unsigned short* __restrict__ T1,
    const float* __restrict__ W2, unsigned short* __restrict__ T2,
    const float* __restrict__ W3, unsigned short* __restrict__ T3)
{
  const float* W; unsigned short* T; int K, N;
  switch (blockIdx.z) {
    case 0:  W = W0; T = T0; K = 768;  N = 3224; break;
    case 1:  W = W1; T = T1; K = 768;  N = 768;  break;
    case 2:  W = W2; T = T2; K = 1536; N = 768;  break;
    default: W = W3; T = T3; K = 768;  N = 768;  break;
  }
  const int n0 = blockIdx.x * 32, k0 = blockIdx.y * 32;
  if (n0 >= N || k0 >= K) return;
  __shared__ float tile[32][33];
  const int tid = threadIdx.x;
  const int tx = tid & 31, ty = tid >> 5;           // 32 x 8
  #pragma unroll
  for (int r = 0; r < 4; r++) {
    int k = k0 + ty + 8*r;
    if (k < K && n0 + tx < N) tile[ty + 8*r][tx] = W[(size_t)k * N + n0 + tx];
  }
  __syncthreads();
  #pragma unroll
  for (int r = 0; r < 4; r++) {
    int n = n0 + ty + 8*r, k = k0 + tx;
    if (n < N && k < K) T[(size_t)n * K + k] = f2bf(tile[tx][ty + 8*r]);
  }
}

// ======== 128x128 GEMM core: C[M][N] = A[M][K] @ Bt[N][K]^T, BK=64 ===============
// LDS swizzle: slot j of row r holds k-granule g = j ^ (r&7)  (granule = 16B).
// epi: 0 plain, 1 sigmoid(C+bias[n]), 2 C+bias[n]+resid[m][n].  Cb!=null -> bf16 out.
__device__ __forceinline__ void gemm_core(const unsigned short* __restrict__ A,
    const unsigned short* __restrict__ Bt, float* __restrict__ C,
    unsigned short* __restrict__ Cb,
    int M, int N, int K, int epi, const float* __restrict__ bias,
    const float* __restrict__ resid, int m0, int n0,
    unsigned short* As, unsigned short* Bs)
{
  const int tid = threadIdx.x;
  const int lane = tid & 63, w = tid >> 6;
  const int wm = (w >> 1) * 64, wn = (w & 1) * 64;
  const int l15 = lane & 15, lq = lane >> 4;
  const int sw = l15 & 7;                  // fragment-read swizzle
  f32x4 acc[4][4];
  #pragma unroll
  for (int i = 0; i < 4; i++)
    #pragma unroll
    for (int j = 0; j < 4; j++) acc[i][j] = (f32x4){0.f, 0.f, 0.f, 0.f};

  int rowg[4], gq[4];
  #pragma unroll
  for (int r = 0; r < 4; r++) {
    int gi = (r * 4 + w) * 64 + lane;
    rowg[r] = gi >> 3;
    gq[r] = (gi & 7) ^ (rowg[r] & 7);
  }

  for (int k0 = 0; k0 < K; k0 += 64) {
    __syncthreads();
    #pragma unroll
    for (int r = 0; r < 4; r++)
      gld16(A + (size_t)(m0 + rowg[r]) * K + k0 + gq[r] * 8, &As[(r * 4 + w) * 512]);
    #pragma unroll
    for (int r = 0; r < 4; r++) {
      int nr = n0 + rowg[r]; if (nr >= N) nr = N - 1;   // clamp; cols >= N masked in epilogue
      gld16(Bt + (size_t)nr * K + k0 + gq[r] * 8, &Bs[(r * 4 + w) * 512]);
    }
    __syncthreads();
    #pragma unroll
    for (int ks = 0; ks < 2; ks++) {
      short8 a8[4], b8[4];
      #pragma unroll
      for (int mi = 0; mi < 4; mi++)
        a8[mi] = *(const short8*)(&As[(wm + 16 * mi + l15) * 64 + ((lq + 4 * ks) ^ sw) * 8]);
      #pragma unroll
      for (int ni = 0; ni < 4; ni++)
        b8[ni] = *(const short8*)(&Bs[(wn + 16 * ni + l15) * 64 + ((lq + 4 * ks) ^ sw) * 8]);
      #pragma unroll
      for (int mi = 0; mi < 4; mi++)
        #pragma unroll
        for (int ni = 0; ni < 4; ni++)
          acc[mi][ni] = __builtin_amdgcn_mfma_f32_16x16x32_bf16(a8[mi], b8[ni], acc[mi][ni], 0, 0, 0);
    }
  }
  #pragma unroll
  for (int mi = 0; mi < 4; mi++) {
    #pragma unroll
    for (int r = 0; r < 4; r++) {
      int row = m0 + wm + 16*mi + lq*4 + r;
      #pragma unroll
      for (int ni = 0; ni < 4; ni++) {
        int col = n0 + wn + 16*ni + l15;
        if (col < N) {
          float vv = acc[mi][ni][r];
          if (epi == 1)      vv = sigm(vv + bias[col]);
          else if (epi == 2) vv = vv + bias[col] + resid[(size_t)row * N + col];
          if (Cb) Cb[(size_t)row * N + col] = f2bf(vv);
          else    C [(size_t)row * N + col] = vv;
        }
      }
    }
  }
}

__global__ __launch_bounds__(256) void k_gemm(const unsigned short* __restrict__ A,
    const unsigned short* __restrict__ Bt, float* __restrict__ C,
    unsigned short* __restrict__ Cb,
    int M, int N, int K, int epi, const float* __restrict__ bias,
    const float* __restrict__ resid)
{
  __shared__ alignas(16) unsigned short As[128 * 64];
  __shared__ alignas(16) unsigned short Bs[128 * 64];
  gemm_core(A, Bt, C, Cb, M, N, K, epi, bias, resid,
            blockIdx.y * 128, blockIdx.x * 128, As, Bs);
}

// two independent bf16-out GEMMs in one dispatch (z-plane):
// z=0: out_proj  YN @ WOPT -> YPb (K=1536)    z=1: gate XN @ WGT -> Gb (K=768, sigmoid)
__global__ __launch_bounds__(256) void k_dualgemm(
    const unsigned short* __restrict__ A0, const unsigned short* __restrict__ B0,
    unsigned short* __restrict__ C0, int K0,
    const unsigned short* __restrict__ A1, const unsigned short* __restrict__ B1,
    unsigned short* __restrict__ C1, int K1, const float* __restrict__ bias1, int N)
{
  __shared__ alignas(16) unsigned short As[128 * 64];
  __shared__ alignas(16) unsigned short Bs[128 * 64];
  if (blockIdx.z == 0)
    gemm_core(A0, B0, nullptr, C0, NTOK, N, K0, 0, nullptr, nullptr,
              blockIdx.y * 128, blockIdx.x * 128, As, Bs);
  else
    gemm_core(A1, B1, nullptr, C1, NTOK, N, K1, 1, bias1, nullptr,
              blockIdx.y * 128, blockIdx.x * 128, As, Bs);
}

// ---------------- LDS-tiled causal conv1d (K=4) + SiLU ---------------------------
// block = 64 tokens x 128 channels; stage 67x128 window in LDS, weights in regs.
__global__ __launch_bounds__(256) void k_conv(const unsigned short* __restrict__ zx,
    const float* __restrict__ cw, const float* __restrict__ cb,
    unsigned short* __restrict__ out)
{
  __shared__ alignas(8) unsigned short tile[67][132];   // pitch 264 B (8B-divisible)
  const int tid = threadIdx.x;
  const int c0 = blockIdx.x * 128;          // 13 tiles x 128 = 1664 = CONVD
  const int tc = blockIdx.y;                // 128 token-chunks of 64
  const int t0 = tc * 64;
  const bool haloOK = (tc & 63) != 0;       // chunk 0 of each batch has no halo
  // ---- stage: rows t0-3 .. t0+63, channels c0..c0+127 ----
  for (int i = tid; i < 67 * 16; i += 256) {   // 16 granules of 8ch x 16B? no: 16 x 8ch... 128ch/8 = 16 granules of 16B
    int row = i >> 4, g = i & 15;
    unsigned long long v0 = 0, v1 = 0;
    if (row >= 3 || haloOK) {
      const unsigned short* p = zx + (size_t)(t0 - 3 + row) * DINPROJ + DINNER + c0 + g * 8;
      v0 = *(const unsigned long long*)p;
      v1 = *(const unsigned long long*)(p + 4);
    }
    *(unsigned long long*)(&tile[row][g * 8])     = v0;
    *(unsigned long long*)(&tile[row][g * 8 + 4]) = v1;
  }
  __syncthreads();
  // ---- compute: thread -> 2 channels x 16 tokens ----
  const int ch0 = (tid & 63) * 2;           // 0..126
  const int trow = tid >> 6;                // 0..3
  const int cg = c0 + ch0;
  float cw0[4], cw1[4];
  #pragma unroll
  for (int k = 0; k < 4; k++) { cw0[k] = cw[cg * 4 + k]; cw1[k] = cw[(cg + 1) * 4 + k]; }
  const float cb0 = cb[cg], cb1 = cb[cg + 1];
  #pragma unroll
  for (int q = 0; q < 16; q++) {
    int tq = trow * 16 + q;
    float a0 = cb0, a1 = cb1;
    #pragma unroll
    for (int k = 0; k < 4; k++) {
      unsigned int u = *(const unsigned int*)(&tile[tq + k][ch0]);
      a0 += bf2f((unsigned short)u) * cw0[k];
      a1 += bf2f((unsigned short)(u >> 16)) * cw1[k];
    }
    float s0 = a0 * sigm(a0), s1 = a1 * sigm(a1);
    *(unsigned int*)(out + (size_t)(t0 + tq) * CONVD + cg) =
        (unsigned int)f2bf(s0) | ((unsigned int)f2bf(s1) << 16);
  }
}

// ---------------- SSD pass 1 (MFMA): S[bh,c][n][p] = sum_s (B[s][n]*wv[s]) X[s][p]
__global__ __launch_bounds__(256) void k_chunkstate(const unsigned short* __restrict__ zx,
    const unsigned short* __restrict__ xbcc, const float* __restrict__ dt_bias,
    const float* __restrict__ A_log, float* __restrict__ S, float* __restrict__ CD)
{
  const int c = blockIdx.x, bh = blockIdx.y;
  const int b = bh / NH, h = bh % NH;
  const int tid = threadIdx.x;
  const int lane = tid & 63, w = tid >> 6;
  const int l15 = lane & 15, lq = lane >> 4;
  __shared__ float wv_[64];
  __shared__ alignas(16) unsigned short Bwt[64][LP];  // [n][s]
  __shared__ alignas(16) unsigned short Xt [64][LP];  // [p][s]

  if (tid < 64) {                     // wave 0: dt, prefix-scan of Lc
    int t = c * 64 + tid;
    float xx = bf2f(zx[((size_t)(b * SEQ + t)) * DINPROJ + (DINNER + CONVD) + h]) + dt_bias[h];
    float dt_ = (xx > 15.f) ? xx : log1pf(__expf(xx));
    float Ah = -__expf(A_log[h]);
    float v = dt_ * Ah;
    #pragma unroll
    for (int off = 1; off < 64; off <<= 1) {
      float u = __shfl_up(v, off);
      if (tid >= off) v += u;
    }
    float L63 = __shfl(v, 63);
    wv_[tid] = __expf(L63 - v) * dt_;
    if (tid == 63) CD[bh * 64 + c] = __expf(v);
  }
  unsigned long long braw[4];
  #pragma unroll
  for (int it = 0; it < 4; it++) {
    int i4 = tid + 256 * it;
    int s = i4 >> 4, q4 = (i4 & 15) * 4;
    size_t rb = ((size_t)(b * SEQ) + c * 64 + s) * CONVD;
    braw[it] = *(const unsigned long long*)(xbcc + rb + DINNER + q4);
    unsigned short xs[4];
    *(unsigned long long*)xs = *(const unsigned long long*)(xbcc + rb + h * HD + q4);
    Xt[q4+0][s] = xs[0]; Xt[q4+1][s] = xs[1]; Xt[q4+2][s] = xs[2]; Xt[q4+3][s] = xs[3];
  }
  __syncthreads();
  #pragma unroll
  for (int it = 0; it < 4; it++) {
    int i4 = tid + 256 * it;
    int s = i4 >> 4, q4 = (i4 & 15) * 4;
    float wsc = wv_[s];
    unsigned short us[4];
    *(unsigned long long*)us = braw[it];
    Bwt[q4+0][s] = f2bf(bf2f(us[0]) * wsc);
    Bwt[q4+1][s] = f2bf(bf2f(us[1]) * wsc);
    Bwt[q4+2][s] = f2bf(bf2f(us[2]) * wsc);
    Bwt[q4+3][s] = f2bf(bf2f(us[3]) * wsc);
  }
  __syncthreads();
  const int n0 = 16 * w;
  short8 a0 = *(const short8*)(&Bwt[n0 + l15][lq * 8]);
  short8 a1 = *(const short8*)(&Bwt[n0 + l15][32 + lq * 8]);
  size_t sb = ((size_t)bh * 64 + c) * 4096;
  #pragma unroll
  for (int pt = 0; pt < 4; pt++) {
    f32x4 acc = (f32x4){0.f, 0.f, 0.f, 0.f};
    short8 b0 = *(const short8*)(&Xt[16*pt + l15][lq * 8]);
    short8 b1 = *(const short8*)(&Xt[16*pt + l15][32 + lq * 8]);
    acc = __builtin_amdgcn_mfma_f32_16x16x32_bf16(a0, b0, acc, 0, 0, 0);
    acc = __builtin_amdgcn_mfma_f32_16x16x32_bf16(a1, b1, acc, 0, 0, 0);
    #pragma unroll
    for (int r = 0; r < 4; r++) {
      int n = n0 + 4*lq + r, p = 16*pt + l15;
      S[sb + (size_t)n * 64 + p] = acc[r];
    }
  }
}

// ---------------- SSD pass 2: chunk-level recurrence (in-place S -> G) -----------
__global__ __launch_bounds__(256) void k_chunkrec(float* __restrict__ S,
    const float* __restrict__ CD)
{
  const int bh = blockIdx.x >> 4, part = blockIdx.x & 15;
  const int e = part * 256 + threadIdx.x;
  float g = 0.f;
  size_t base = (size_t)bh * 64 * 4096 + e;
  for (int c = 0; c < 64; c++) {
    size_t ad = base + (size_t)c * 4096;
    float sv = S[ad];
    float pc = CD[bh * 64 + c];
    S[ad] = g;               // slot c now holds G_c (state before chunk c)
    g = pc * g + sv;
  }
}

// ---------------- SSD pass 3 (MFMA): per-chunk outputs (bf16 Y out) --------------
__global__ __launch_bounds__(256) void k_chunkout(const unsigned short* __restrict__ zx,
    const unsigned short* __restrict__ xbcc, const float* __restrict__ S,
    const float* __restrict__ dt_bias, const float* __restrict__ A_log,
    const float* __restrict__ Dp, unsigned short* __restrict__ Y)
{
  const int c = blockIdx.x, bh = blockIdx.y;
  const int b = bh / NH, h = bh % NH;
  const int tid = threadIdx.x;
  const int lane = tid & 63, w = tid >> 6;
  const int l15 = lane & 15, lq = lane >> 4;
  __shared__ float dts[64], Lc[64], ein[64];
  __shared__ alignas(16) unsigned short Cs  [64][LP];  // [i][n]
  __shared__ alignas(16) unsigned short BsPs[64][LP];  // [s][n], then P[i][s]
  __shared__ alignas(16) unsigned short Xt  [64][LP];  // [p][s]
  __shared__ alignas(16) unsigned short Gt  [64][LP];  // [p][n]

  if (tid < 64) {                     // wave 0: dt, prefix-scan of Lc
    int t = c * 64 + tid;
    float xx = bf2f(zx[((size_t)(b * SEQ + t)) * DINPROJ + (DINNER + CONVD) + h]) + dt_bias[h];
    float dt_ = (xx > 15.f) ? xx : log1pf(__expf(xx));
    dts[tid] = dt_;
    float Ah = -__expf(A_log[h]);
    float v = dt_ * Ah;
    #pragma unroll
    for (int off = 1; off < 64; off <<= 1) {
      float u = __shfl_up(v, off);
      if (tid >= off) v += u;
    }
    Lc[tid] = v;
    ein[tid] = __expf(v);
  }
  const size_t gslot = ((size_t)bh * 64 + c) * 4096;
  #pragma unroll
  for (int it = 0; it < 4; it++) {
    int i4 = tid + 256 * it;
    int rr = i4 >> 4, q4 = (i4 & 15) * 4;
    size_t rb = ((size_t)(b * SEQ) + c * 64 + rr) * CONVD;
    const unsigned short* pC = xbcc + rb + (DINNER + DSTATE) + q4;
    Cs[rr][q4+0] = pC[0]; Cs[rr][q4+1] = pC[1]; Cs[rr][q4+2] = pC[2]; Cs[rr][q4+3] = pC[3];
    const unsigned short* pB = xbcc + rb + DINNER + q4;
    BsPs[rr][q4+0] = pB[0]; BsPs[rr][q4+1] = pB[1]; BsPs[rr][q4+2] = pB[2]; BsPs[rr][q4+3] = pB[3];
    *(unsigned long long*)(&Xt[0][0]) = *(unsigned long long*)(&Xt[0][0]);  // no-op keepalive
    unsigned short xs[4];
    *(unsigned long long*)xs = *(const unsigned long long*)(xbcc + rb + h * HD + q4);
    Xt[q4+0][rr] = xs[0]; Xt[q4+1][rr] = xs[1]; Xt[q4+2][rr] = xs[2]; Xt[q4+3][rr] = xs[3];
    float4 vG = *(const float4*)(S + gslot + (size_t)i4 * 4);   // row n=rr, cols q4..q4+3
    Gt[q4+0][rr] = f2bf(vG.x); Gt[q4+1][rr] = f2bf(vG.y);
    Gt[q4+2][rr] = f2bf(vG.z); Gt[q4+3][rr] = f2bf(vG.w);
  }
  __syncthreads();
  // ---- matmul1: G[i][s] = sum_n C[i][n] B[s][n]; apply causal decay mask -> P ----
  const int i0 = 16 * w;
  short8 ac0 = *(const short8*)(&Cs[i0 + l15][lq * 8]);
  short8 ac1 = *(const short8*)(&Cs[i0 + l15][32 + lq * 8]);
  float pp[4][4];
  #pragma unroll
  for (int st = 0; st < 4; st++) {
    f32x4 g = (f32x4){0.f, 0.f, 0.f, 0.f};
    if (st <= w) {                                   // wave-uniform causal skip
      short8 b0 = *(const short8*)(&BsPs[16*st + l15][lq * 8]);
      short8 b1 = *(const short8*)(&BsPs[16*st + l15][32 + lq * 8]);
      g = __builtin_amdgcn_mfma_f32_16x16x32_bf16(ac0, b0, g, 0, 0, 0);
      g = __builtin_amdgcn_mfma_f32_16x16x32_bf16(ac1, b1, g, 0, 0, 0);
    }
    #pragma unroll
    for (int r = 0; r < 4; r++) {
      int i = i0 + 4*lq + r, s = 16*st + l15;
      pp[st][r] = (s <= i) ? g[r] * __expf(Lc[i] - Lc[s]) * dts[s] : 0.f;
    }
  }
  __syncthreads();                                   // all waves done reading Bs
  #pragma unroll
  for (int st = 0; st < 4; st++)
    #pragma unroll
    for (int r = 0; r < 4; r++)
      BsPs[i0 + 4*lq + r][16*st + l15] = f2bf(pp[st][r]);   // P[i][s], s contiguous
  __syncthreads();
  // ---- matmul2+3: Y[i][p] = P@X + ein[i]*(C@G) + D*x ----
  short8 ap0 = *(const short8*)(&BsPs[i0 + l15][lq * 8]);
  short8 ap1 = *(const short8*)(&BsPs[i0 + l15][32 + lq * 8]);
  const float Dh = Dp[h];
  #pragma unroll
  for (int pt = 0; pt < 4; pt++) {
    const int p0 = 16 * pt;
    f32x4 y1 = (f32x4){0.f, 0.f, 0.f, 0.f};
    f32x4 y2 = (f32x4){0.f, 0.f, 0.f, 0.f};
    short8 bx0 = *(const short8*)(&Xt[p0 + l15][lq * 8]);
    y1 = __builtin_amdgcn_mfma_f32_16x16x32_bf16(ap0, bx0, y1, 0, 0, 0);
    if (w >= 2) {                                    // P rows of wave w have k < 16(w+1)
      short8 bx1 = *(const short8*)(&Xt[p0 + l15][32 + lq * 8]);
      y1 = __builtin_amdgcn_mfma_f32_16x16x32_bf16(ap1, bx1, y1, 0, 0, 0);
    }
    short8 bg0 = *(const short8*)(&Gt[p0 + l15][lq * 8]);
    short8 bg1 = *(const short8*)(&Gt[p0 + l15][32 + lq * 8]);
    y2 = __builtin_amdgcn_mfma_f32_16x16x32_bf16(ac0, bg0, y2, 0, 0, 0);
    y2 = __builtin_amdgcn_mfma_f32_16x16x32_bf16(ac1, bg1, y2, 0, 0, 0);
    #pragma unroll
    for (int r = 0; r < 4; r++) {
      int i = i0 + 4*lq + r, p = p0 + l15;
      float xv = bf2f(Xt[p][i]);
      float o = y1[r] + ein[i] * y2[r] + Dh * xv;
      Y[((size_t)(b * SEQ) + c * 64 + i) * DINNER + h * HD + p] = f2bf(o);
    }
  }
}

// ---------------- y*silu(z), RMSNorm -> bf16 -------------------------------------
__global__ __launch_bounds__(256) void k_fuse(const unsigned short* __restrict__ Y,
    const unsigned short* __restrict__ ZX, const float* __restrict__ rw,
    unsigned short* __restrict__ YN)
{
  __shared__ float red[4];
  const int row = blockIdx.x, tid = threadIdx.x;
  const unsigned short* yr = Y + (size_t)row * DINNER;
  const unsigned short* zr = ZX + (size_t)row * DINPROJ;
  float v[6]; float s2 = 0.f;
  #pragma unroll
  for (int q = 0; q < 6; q++) {
    int col = q * 256 + tid;
    float z = bf2f(zr[col]);
    float yv = bf2f(yr[col]) * (z * sigm(z));
    v[q] = yv; s2 += yv * yv;
  }
  #pragma unroll
  for (int off = 32; off; off >>= 1) s2 += __shfl_down(s2, off);
  if ((tid & 63) == 0) red[tid >> 6] = s2;
  __syncthreads();
  const float rs = rsqrtf((red[0] + red[1] + red[2] + red[3]) * (1.f / DINNER) + EPSF);
  unsigned short* yo = YN + (size_t)row * DINNER;
  #pragma unroll
  for (int q = 0; q < 6; q++) {
    int col = q * 256 + tid;
    yo[col] = f2bf(v[q] * rs * rw[col]);
  }
}

// ---------------- yg = bf16(yproj * gate), 4 elems/thread ------------------------
__global__ __launch_bounds__(256) void k_gatemul(const unsigned short* __restrict__ YP,
    const unsigned short* __restrict__ G, unsigned short* __restrict__ YG)
{
  size_t i4 = ((size_t)blockIdx.x * 256 + threadIdx.x) * 4;
  unsigned short a[4], b[4];
  *(unsigned long long*)a = *(const unsigned long long*)(YP + i4);
  *(unsigned long long*)b = *(const unsigned long long*)(G + i4);
  *(unsigned long long*)(YG + i4) = pack4bf(
      bf2f(a[0]) * bf2f(b[0]), bf2f(a[1]) * bf2f(b[1]),
      bf2f(a[2]) * bf2f(b[2]), bf2f(a[3]) * bf2f(b[3]));
}

// ---------------- launch ----------------------------------------------------------
extern "C" void kernel_launch(void* const* d_in, const int* in_sizes, int n_in,
                              void* d_out, int out_size, void* d_ws, size_t ws_size,
                              hipStream_t stream)
{
  const float* x         = (const float*)d_in[0];
  const float* ln_w      = (const float*)d_in[1];
  const float* ln_b      = (const float*)d_in[2];
  const float* in_proj_w = (const float*)d_in[3];
  const float* conv_w    = (const float*)d_in[4];
  const float* conv_b    = (const float*)d_in[5];
  const float* dt_bias   = (const float*)d_in[6];
  const float* A_log     = (const float*)d_in[7];
  const float* D_param   = (const float*)d_in[8];
  const float* rms_w     = (const float*)d_in[9];
  const float* out_proj_w= (const float*)d_in[10];
  const float* gate_w    = (const float*)d_in[11];
  const float* gate_b    = (const float*)d_in[12];
  const float* out_w     = (const float*)d_in[13];
  const float* out_b     = (const float*)d_in[14];
  float* out = (float*)d_out;
  char* ws = (char*)d_ws;

  // ---- workspace layout (bytes). peak = 177,848,320 B (~170 MB) ----
  const size_t WS_NEEDED = 177848320ull;
  if (ws_size < WS_NEEDED) return;

  unsigned short* XN    = (unsigned short*)(ws + 0);
  unsigned short* WIT   = (unsigned short*)(ws + 12582912);
  unsigned short* WGT   = (unsigned short*)(ws + 17534976);
  unsigned short* WOPT  = (unsigned short*)(ws + 18714624);
  unsigned short* WOT   = (unsigned short*)(ws + 21073920);
  unsigned short* ZXb   = (unsigned short*)(ws + 22253568);   // 8192x3224 bf16
  unsigned short* XBCCb = (unsigned short*)(ws + 75075584);   // 8192x1664 bf16
  float*          SG    = (float*)(ws + 102338560);           // 3072x4096 f32
  float*          CD    = (float*)(ws + 152670208);           // 3072 f32
  unsigned short* Yb    = (unsigned short*)(ws + 152682496);  // 8192x1536 bf16
  // overlays:
  unsigned short* YN    = (unsigned short*)(ws + 102338560);  // in SG region (dead after chunkout)
  unsigned short* Gb    = (unsigned short*)(ws + 22253568);   // in ZXb region (dead after fuse)
  unsigned short* YPb   = (unsigned short*)(ws + 34836480);   // in ZXb region
  unsigned short* YG    = (unsigned short*)(ws + 75075584);   // in XBCCb region (dead after chunkout)

  // 1) weight converts, single dispatch
  k_wtrans4<<<dim3(101, 48, 4), 256, 0, stream>>>(in_proj_w, WIT, gate_w, WGT,
                                                  out_proj_w, WOPT, out_w, WOT);
  // 2) layernorm
  k_ln<<<NTOK, 256, 0, stream>>>(x, ln_w, ln_b, XN);
  // 3) in_proj GEMM -> zxbcdt (bf16), proven 128x128 config
  k_gemm<<<dim3(26, 64), 256, 0, stream>>>(XN, WIT, nullptr, ZXb, NTOK, DINPROJ, DMODEL, 0, nullptr, nullptr);
  // 4) LDS-tiled causal conv + silu (bf16 -> bf16)
  k_conv<<<dim3(13, 128), 256, 0, stream>>>(ZXb, conv_w, conv_b, XBCCb);
  // 5-7) SSD scan (R5-proven kernels)
  k_chunkstate<<<dim3(NCHUNK, BSZ * NH), 256, 0, stream>>>(ZXb, XBCCb, dt_bias, A_log, SG, CD);
  k_chunkrec<<<BSZ * NH * 16, 256, 0, stream>>>(SG, CD);
  k_chunkout<<<dim3(NCHUNK, BSZ * NH), 256, 0, stream>>>(ZXb, XBCCb, SG, dt_bias, A_log, D_param, Yb);
  // 8) y*silu(z) + RMSNorm -> bf16 (YN lands in dead SG region)
  k_fuse<<<NTOK, 256, 0, stream>>>(Yb, ZXb, rms_w, YN);
  // 9+10) gate GEMM (sigmoid) + out_proj GEMM, one dispatch, bf16 outputs
  k_dualgemm<<<dim3(6, 64, 2), 256, 0, stream>>>(YN, WOPT, YPb, DINNER,
                                                 XN, WGT, Gb, DMODEL, gate_b, DMODEL);
  // 11) gate multiply -> bf16
  k_gatemul<<<(NTOK * DMODEL / 4) / 256, 256, 0, stream>>>(YPb, Gb, YG);
  // 12) final GEMM + bias + residual -> d_out
  k_gemm<<<dim3(6, 64), 256, 0, stream>>>(YG, WOT, out, nullptr, NTOK, DMODEL, DMODEL, 2, out_b, x);
}

// Round 10
// 410.718 us; speedup vs baseline: 1.9718x; 1.0177x over previous
//
#include <hip/hip_runtime.h>
#include <hip/hip_bf16.h>
#include <cstddef>

// ---------------- problem constants ----------------
#define DMODEL  768
#define DINNER  1536
#define DSTATE  64
#define NH      24
#define HD      64
#define CONVD   1664      // DINNER + 2*DSTATE
#define DINPROJ 3224      // 2*DINNER + 2*DSTATE + NH
#define SEQ     4096
#define BSZ     2
#define NTOK    8192      // BSZ*SEQ
#define NCHUNK  64        // SEQ/64
#define EPSF    1e-5f
#define LP      72        // LDS pitch (shorts) for SSD kernels

typedef __attribute__((ext_vector_type(8))) short  short8;
typedef __attribute__((ext_vector_type(4))) float  f32x4;

// ---------------- helpers ----------------
__device__ __forceinline__ unsigned short f2bf(float f) {
  union { float f; unsigned int u; } v; v.f = f;
  unsigned int r = v.u + 0x7fffu + ((v.u >> 16) & 1u);   // RNE
  return (unsigned short)(r >> 16);
}
__device__ __forceinline__ float bf2f(unsigned short u) {
  union { unsigned int i; float f; } v; v.i = ((unsigned int)u) << 16; return v.f;
}
__device__ __forceinline__ unsigned long long pack4bf(float a, float b, float c, float d) {
  return (unsigned long long)(f2bf(a) | ((unsigned int)f2bf(b) << 16))
       | ((unsigned long long)(f2bf(c) | ((unsigned int)f2bf(d) << 16)) << 32);
}
__device__ __forceinline__ float sigm(float x) { return 1.f / (1.f + __expf(-x)); }

// async 16B global -> LDS (lane i of the wave lands at ldsbase + i*16)
__device__ __forceinline__ void gld16(const unsigned short* g, unsigned short* l) {
  __builtin_amdgcn_global_load_lds(
      (const __attribute__((address_space(1))) unsigned int*)g,
      (__attribute__((address_space(3))) unsigned int*)l, 16, 0, 0);
}

// XCD-aware tile remap: XCD (id&7) owns a contiguous 1/8 of the m-tiles, all n.
// Requires gridDim.y (m-tiles) divisible by 8. Shrinks per-XCD-L2 A footprint.
__device__ __forceinline__ void xcd_tiles(int& m0, int& n0) {
  const int nt = gridDim.x, mt = gridDim.y;
  const int id = blockIdx.y * nt + blockIdx.x;
  const int mper = mt >> 3;
  const int xcd = id & 7, within = id >> 3;
  m0 = (xcd * mper + (within % mper)) * 128;
  n0 = (within / mper) * 128;
}

// ---------------- LayerNorm -> bf16 ----------------
__global__ __launch_bounds__(256) void k_ln(const float* __restrict__ x,
    const float* __restrict__ w, const float* __restrict__ b,
    unsigned short* __restrict__ xn)
{
  __shared__ float red[4];
  const int row = blockIdx.x, tid = threadIdx.x;
  const float* xr = x + (size_t)row * DMODEL;
  float v[3]; float s = 0.f;
  #pragma unroll
  for (int q = 0; q < 3; q++) { v[q] = xr[q*256 + tid]; s += v[q]; }
  #pragma unroll
  for (int off = 32; off; off >>= 1) s += __shfl_down(s, off);
  if ((tid & 63) == 0) red[tid >> 6] = s;
  __syncthreads();
  const float mu = (red[0] + red[1] + red[2] + red[3]) * (1.f / DMODEL);
  __syncthreads();
  float s2 = 0.f;
  #pragma unroll
  for (int q = 0; q < 3; q++) { float d = v[q] - mu; s2 += d * d; }
  #pragma unroll
  for (int off = 32; off; off >>= 1) s2 += __shfl_down(s2, off);
  if ((tid & 63) == 0) red[tid >> 6] = s2;
  __syncthreads();
  const float rs = rsqrtf((red[0] + red[1] + red[2] + red[3]) * (1.f / DMODEL) + EPSF);
  unsigned short* xo = xn + (size_t)row * DMODEL;
  #pragma unroll
  for (int q = 0; q < 3; q++) {
    int col = q*256 + tid;
    xo[col] = f2bf((v[q] - mu) * rs * w[col] + b[col]);
  }
}

// ---------------- 4 weight transposes in one dispatch (z-indexed) ----------------
__global__ __launch_bounds__(256) void k_wtrans4(
    const float* __restrict__ W0, unsigned short* __restrict__ T0,
    const float* __restrict__ W1, unsigned short* __restrict__ T1,
    const float* __restrict__ W2, unsigned short* __restrict__ T2,
    const float* __restrict__ W3, unsigned short* __restrict__ T3)
{
  const float* W; unsigned short* T; int K, N;
  switch (blockIdx.z) {
    case 0:  W = W0; T = T0; K = 768;  N = 3224; break;
    case 1:  W = W1; T = T1; K = 768;  N = 768;  break;
    case 2:  W = W2; T = T2; K = 1536; N = 768;  break;
    default: W = W3; T = T3; K = 768;  N = 768;  break;
  }
  const int n0 = blockIdx.x * 32, k0 = blockIdx.y * 32;
  if (n0 >= N || k0 >= K) return;
  __shared__ float tile[32][33];
  const int tid = threadIdx.x;
  const int tx = tid & 31, ty = tid >> 5;           // 32 x 8
  #pragma unroll
  for (int r = 0; r < 4; r++) {
    int k = k0 + ty + 8*r;
    if (k < K && n0 + tx < N) tile[ty + 8*r][tx] = W[(size_t)k * N + n0 + tx];
  }
  __syncthreads();
  #pragma unroll
  for (int r = 0; r < 4; r++) {
    int n = n0 + ty + 8*r, k = k0 + tx;
    if (n < N && k < K) T[(size_t)n * K + k] = f2bf(tile[tx][ty + 8*r]);
  }
}

// ======== 128x128 GEMM core: C[M][N] = A[M][K] @ Bt[N][K]^T, BK=64 ===============
// LDS swizzle: slot j of row r holds k-granule g = j ^ (r&7)  (granule = 16B).
// epi: 0 plain, 1 sigmoid(C+bias[n]), 2 C+bias[n]+resid[m][n].  Cb!=null -> bf16 out.
__device__ __forceinline__ void gemm_core(const unsigned short* __restrict__ A,
    const unsigned short* __restrict__ Bt, float* __restrict__ C,
    unsigned short* __restrict__ Cb,
    int M, int N, int K, int epi, const float* __restrict__ bias,
    const float* __restrict__ resid, int m0, int n0,
    unsigned short* As, unsigned short* Bs)
{
  const int tid = threadIdx.x;
  const int lane = tid & 63, w = tid >> 6;
  const int wm = (w >> 1) * 64, wn = (w & 1) * 64;
  const int l15 = lane & 15, lq = lane >> 4;
  const int sw = l15 & 7;                  // fragment-read swizzle
  f32x4 acc[4][4];
  #pragma unroll
  for (int i = 0; i < 4; i++)
    #pragma unroll
    for (int j = 0; j < 4; j++) acc[i][j] = (f32x4){0.f, 0.f, 0.f, 0.f};

  int rowg[4], gq[4];
  #pragma unroll
  for (int r = 0; r < 4; r++) {
    int gi = (r * 4 + w) * 64 + lane;
    rowg[r] = gi >> 3;
    gq[r] = (gi & 7) ^ (rowg[r] & 7);
  }

  for (int k0 = 0; k0 < K; k0 += 64) {
    __syncthreads();
    #pragma unroll
    for (int r = 0; r < 4; r++)
      gld16(A + (size_t)(m0 + rowg[r]) * K + k0 + gq[r] * 8, &As[(r * 4 + w) * 512]);
    #pragma unroll
    for (int r = 0; r < 4; r++) {
      int nr = n0 + rowg[r]; if (nr >= N) nr = N - 1;   // clamp; cols >= N masked in epilogue
      gld16(Bt + (size_t)nr * K + k0 + gq[r] * 8, &Bs[(r * 4 + w) * 512]);
    }
    __syncthreads();
    #pragma unroll
    for (int ks = 0; ks < 2; ks++) {
      short8 a8[4], b8[4];
      #pragma unroll
      for (int mi = 0; mi < 4; mi++)
        a8[mi] = *(const short8*)(&As[(wm + 16 * mi + l15) * 64 + ((lq + 4 * ks) ^ sw) * 8]);
      #pragma unroll
      for (int ni = 0; ni < 4; ni++)
        b8[ni] = *(const short8*)(&Bs[(wn + 16 * ni + l15) * 64 + ((lq + 4 * ks) ^ sw) * 8]);
      #pragma unroll
      for (int mi = 0; mi < 4; mi++)
        #pragma unroll
        for (int ni = 0; ni < 4; ni++)
          acc[mi][ni] = __builtin_amdgcn_mfma_f32_16x16x32_bf16(a8[mi], b8[ni], acc[mi][ni], 0, 0, 0);
    }
  }
  #pragma unroll
  for (int mi = 0; mi < 4; mi++) {
    #pragma unroll
    for (int r = 0; r < 4; r++) {
      int row = m0 + wm + 16*mi + lq*4 + r;
      #pragma unroll
      for (int ni = 0; ni < 4; ni++) {
        int col = n0 + wn + 16*ni + l15;
        if (col < N) {
          float vv = acc[mi][ni][r];
          if (epi == 1)      vv = sigm(vv + bias[col]);
          else if (epi == 2) vv = vv + bias[col] + resid[(size_t)row * N + col];
          if (Cb) Cb[(size_t)row * N + col] = f2bf(vv);
          else    C [(size_t)row * N + col] = vv;
        }
      }
    }
  }
}

__global__ __launch_bounds__(256) void k_gemm(const unsigned short* __restrict__ A,
    const unsigned short* __restrict__ Bt, float* __restrict__ C,
    unsigned short* __restrict__ Cb,
    int M, int N, int K, int epi, const float* __restrict__ bias,
    const float* __restrict__ resid)
{
  __shared__ alignas(16) unsigned short As[128 * 64];
  __shared__ alignas(16) unsigned short Bs[128 * 64];
  int m0, n0;
  xcd_tiles(m0, n0);
  gemm_core(A, Bt, C, Cb, M, N, K, epi, bias, resid, m0, n0, As, Bs);
}

// two independent bf16-out GEMMs in one dispatch (z-plane):
// z=0: out_proj  YN @ WOPT -> YPb (K=1536)    z=1: gate XN @ WGT -> Gb (K=768, sigmoid)
__global__ __launch_bounds__(256) void k_dualgemm(
    const unsigned short* __restrict__ A0, const unsigned short* __restrict__ B0,
    unsigned short* __restrict__ C0, int K0,
    const unsigned short* __restrict__ A1, const unsigned short* __restrict__ B1,
    unsigned short* __restrict__ C1, int K1, const float* __restrict__ bias1, int N)
{
  __shared__ alignas(16) unsigned short As[128 * 64];
  __shared__ alignas(16) unsigned short Bs[128 * 64];
  int m0, n0;
  xcd_tiles(m0, n0);
  if (blockIdx.z == 0)
    gemm_core(A0, B0, nullptr, C0, NTOK, N, K0, 0, nullptr, nullptr, m0, n0, As, Bs);
  else
    gemm_core(A1, B1, nullptr, C1, NTOK, N, K1, 1, bias1, nullptr, m0, n0, As, Bs);
}

// ---------------- LDS-tiled causal conv1d (K=4) + SiLU ---------------------------
// block = 64 tokens x 128 channels; stage 67x128 window in LDS, weights in regs.
__global__ __launch_bounds__(256) void k_conv(const unsigned short* __restrict__ zx,
    const float* __restrict__ cw, const float* __restrict__ cb,
    unsigned short* __restrict__ out)
{
  __shared__ alignas(8) unsigned short tile[67][132];   // pitch 264 B
  const int tid = threadIdx.x;
  const int c0 = blockIdx.x * 128;          // 13 tiles x 128 = 1664 = CONVD
  const int tc = blockIdx.y;                // 128 token-chunks of 64
  const int t0 = tc * 64;
  const bool haloOK = (tc & 63) != 0;       // chunk 0 of each batch has no halo
  for (int i = tid; i < 67 * 16; i += 256) {
    int row = i >> 4, g = i & 15;
    unsigned long long v0 = 0, v1 = 0;
    if (row >= 3 || haloOK) {
      const unsigned short* p = zx + (size_t)(t0 - 3 + row) * DINPROJ + DINNER + c0 + g * 8;
      v0 = *(const unsigned long long*)p;
      v1 = *(const unsigned long long*)(p + 4);
    }
    *(unsigned long long*)(&tile[row][g * 8])     = v0;
    *(unsigned long long*)(&tile[row][g * 8 + 4]) = v1;
  }
  __syncthreads();
  const int ch0 = (tid & 63) * 2;           // 0..126
  const int trow = tid >> 6;                // 0..3
  const int cg = c0 + ch0;
  float cw0[4], cw1[4];
  #pragma unroll
  for (int k = 0; k < 4; k++) { cw0[k] = cw[cg * 4 + k]; cw1[k] = cw[(cg + 1) * 4 + k]; }
  const float cb0 = cb[cg], cb1 = cb[cg + 1];
  #pragma unroll
  for (int q = 0; q < 16; q++) {
    int tq = trow * 16 + q;
    float a0 = cb0, a1 = cb1;
    #pragma unroll
    for (int k = 0; k < 4; k++) {
      unsigned int u = *(const unsigned int*)(&tile[tq + k][ch0]);
      a0 += bf2f((unsigned short)u) * cw0[k];
      a1 += bf2f((unsigned short)(u >> 16)) * cw1[k];
    }
    float s0 = a0 * sigm(a0), s1 = a1 * sigm(a1);
    *(unsigned int*)(out + (size_t)(t0 + tq) * CONVD + cg) =
        (unsigned int)f2bf(s0) | ((unsigned int)f2bf(s1) << 16);
  }
}

// ---------------- SSD pass 1 (MFMA): S[bh,c][n][p] = sum_s (B[s][n]*wv[s]) X[s][p]
__global__ __launch_bounds__(256) void k_chunkstate(const unsigned short* __restrict__ zx,
    const unsigned short* __restrict__ xbcc, const float* __restrict__ dt_bias,
    const float* __restrict__ A_log, float* __restrict__ S, float* __restrict__ CD)
{
  const int c = blockIdx.x, bh = blockIdx.y;
  const int b = bh / NH, h = bh % NH;
  const int tid = threadIdx.x;
  const int lane = tid & 63, w = tid >> 6;
  const int l15 = lane & 15, lq = lane >> 4;
  __shared__ float wv_[64];
  __shared__ alignas(16) unsigned short Bwt[64][LP];  // [n][s]
  __shared__ alignas(16) unsigned short Xt [64][LP];  // [p][s]

  if (tid < 64) {                     // wave 0: dt, prefix-scan of Lc
    int t = c * 64 + tid;
    float xx = bf2f(zx[((size_t)(b * SEQ + t)) * DINPROJ + (DINNER + CONVD) + h]) + dt_bias[h];
    float dt_ = (xx > 15.f) ? xx : log1pf(__expf(xx));
    float Ah = -__expf(A_log[h]);
    float v = dt_ * Ah;
    #pragma unroll
    for (int off = 1; off < 64; off <<= 1) {
      float u = __shfl_up(v, off);
      if (tid >= off) v += u;
    }
    float L63 = __shfl(v, 63);
    wv_[tid] = __expf(L63 - v) * dt_;
    if (tid == 63) CD[bh * 64 + c] = __expf(v);
  }
  unsigned long long braw[4];
  #pragma unroll
  for (int it = 0; it < 4; it++) {
    int i4 = tid + 256 * it;
    int s = i4 >> 4, q4 = (i4 & 15) * 4;
    size_t rb = ((size_t)(b * SEQ) + c * 64 + s) * CONVD;
    braw[it] = *(const unsigned long long*)(xbcc + rb + DINNER + q4);
    unsigned short xs[4];
    *(unsigned long long*)xs = *(const unsigned long long*)(xbcc + rb + h * HD + q4);
    Xt[q4+0][s] = xs[0]; Xt[q4+1][s] = xs[1]; Xt[q4+2][s] = xs[2]; Xt[q4+3][s] = xs[3];
  }
  __syncthreads();
  #pragma unroll
  for (int it = 0; it < 4; it++) {
    int i4 = tid + 256 * it;
    int s = i4 >> 4, q4 = (i4 & 15) * 4;
    float wsc = wv_[s];
    unsigned short us[4];
    *(unsigned long long*)us = braw[it];
    Bwt[q4+0][s] = f2bf(bf2f(us[0]) * wsc);
    Bwt[q4+1][s] = f2bf(bf2f(us[1]) * wsc);
    Bwt[q4+2][s] = f2bf(bf2f(us[2]) * wsc);
    Bwt[q4+3][s] = f2bf(bf2f(us[3]) * wsc);
  }
  __syncthreads();
  const int n0 = 16 * w;
  short8 a0 = *(const short8*)(&Bwt[n0 + l15][lq * 8]);
  short8 a1 = *(const short8*)(&Bwt[n0 + l15][32 + lq * 8]);
  size_t sb = ((size_t)bh * 64 + c) * 4096;
  #pragma unroll
  for (int pt = 0; pt < 4; pt++) {
    f32x4 acc = (f32x4){0.f, 0.f, 0.f, 0.f};
    short8 b0 = *(const short8*)(&Xt[16*pt + l15][lq * 8]);
    short8 b1 = *(const short8*)(&Xt[16*pt + l15][32 + lq * 8]);
    acc = __builtin_amdgcn_mfma_f32_16x16x32_bf16(a0, b0, acc, 0, 0, 0);
    acc = __builtin_amdgcn_mfma_f32_16x16x32_bf16(a1, b1, acc, 0, 0, 0);
    #pragma unroll
    for (int r = 0; r < 4; r++) {
      int n = n0 + 4*lq + r, p = 16*pt + l15;
      S[sb + (size_t)n * 64 + p] = acc[r];
    }
  }
}

// ---------------- SSD pass 2: chunk-level recurrence (in-place S -> G) -----------
__global__ __launch_bounds__(256) void k_chunkrec(float* __restrict__ S,
    const float* __restrict__ CD)
{
  const int bh = blockIdx.x >> 4, part = blockIdx.x & 15;
  const int e = part * 256 + threadIdx.x;
  float g = 0.f;
  size_t base = (size_t)bh * 64 * 4096 + e;
  for (int c = 0; c < 64; c++) {
    size_t ad = base + (size_t)c * 4096;
    float sv = S[ad];
    float pc = CD[bh * 64 + c];
    S[ad] = g;               // slot c now holds G_c (state before chunk c)
    g = pc * g + sv;
  }
}

// ---------------- SSD pass 3 (MFMA): per-chunk outputs (bf16 Y out) --------------
__global__ __launch_bounds__(256) void k_chunkout(const unsigned short* __restrict__ zx,
    const unsigned short* __restrict__ xbcc, const float* __restrict__ S,
    const float* __restrict__ dt_bias, const float* __restrict__ A_log,
    const float* __restrict__ Dp, unsigned short* __restrict__ Y)
{
  const int c = blockIdx.x, bh = blockIdx.y;
  const int b = bh / NH, h = bh % NH;
  const int tid = threadIdx.x;
  const int lane = tid & 63, w = tid >> 6;
  const int l15 = lane & 15, lq = lane >> 4;
  __shared__ float dts[64], Lc[64], ein[64];
  __shared__ alignas(16) unsigned short Cs  [64][LP];  // [i][n]
  __shared__ alignas(16) unsigned short BsPs[64][LP];  // [s][n], then P[i][s]
  __shared__ alignas(16) unsigned short Xt  [64][LP];  // [p][s]
  __shared__ alignas(16) unsigned short Gt  [64][LP];  // [p][n]

  if (tid < 64) {                     // wave 0: dt, prefix-scan of Lc
    int t = c * 64 + tid;
    float xx = bf2f(zx[((size_t)(b * SEQ + t)) * DINPROJ + (DINNER + CONVD) + h]) + dt_bias[h];
    float dt_ = (xx > 15.f) ? xx : log1pf(__expf(xx));
    dts[tid] = dt_;
    float Ah = -__expf(A_log[h]);
    float v = dt_ * Ah;
    #pragma unroll
    for (int off = 1; off < 64; off <<= 1) {
      float u = __shfl_up(v, off);
      if (tid >= off) v += u;
    }
    Lc[tid] = v;
    ein[tid] = __expf(v);
  }
  const size_t gslot = ((size_t)bh * 64 + c) * 4096;
  #pragma unroll
  for (int it = 0; it < 4; it++) {
    int i4 = tid + 256 * it;
    int rr = i4 >> 4, q4 = (i4 & 15) * 4;
    size_t rb = ((size_t)(b * SEQ) + c * 64 + rr) * CONVD;
    const unsigned short* pC = xbcc + rb + (DINNER + DSTATE) + q4;
    Cs[rr][q4+0] = pC[0]; Cs[rr][q4+1] = pC[1]; Cs[rr][q4+2] = pC[2]; Cs[rr][q4+3] = pC[3];
    const unsigned short* pB = xbcc + rb + DINNER + q4;
    BsPs[rr][q4+0] = pB[0]; BsPs[rr][q4+1] = pB[1]; BsPs[rr][q4+2] = pB[2]; BsPs[rr][q4+3] = pB[3];
    unsigned short xs[4];
    *(unsigned long long*)xs = *(const unsigned long long*)(xbcc + rb + h * HD + q4);
    Xt[q4+0][rr] = xs[0]; Xt[q4+1][rr] = xs[1]; Xt[q4+2][rr] = xs[2]; Xt[q4+3][rr] = xs[3];
    float4 vG = *(const float4*)(S + gslot + (size_t)i4 * 4);   // row n=rr, cols q4..q4+3
    Gt[q4+0][rr] = f2bf(vG.x); Gt[q4+1][rr] = f2bf(vG.y);
    Gt[q4+2][rr] = f2bf(vG.z); Gt[q4+3][rr] = f2bf(vG.w);
  }
  __syncthreads();
  // ---- matmul1: G[i][s] = sum_n C[i][n] B[s][n]; apply causal decay mask -> P ----
  const int i0 = 16 * w;
  short8 ac0 = *(const short8*)(&Cs[i0 + l15][lq * 8]);
  short8 ac1 = *(const short8*)(&Cs[i0 + l15][32 + lq * 8]);
  float pp[4][4];
  #pragma unroll
  for (int st = 0; st < 4; st++) {
    f32x4 g = (f32x4){0.f, 0.f, 0.f, 0.f};
    if (st <= w) {                                   // wave-uniform causal skip
      short8 b0 = *(const short8*)(&BsPs[16*st + l15][lq * 8]);
      short8 b1 = *(const short8*)(&BsPs[16*st + l15][32 + lq * 8]);
      g = __builtin_amdgcn_mfma_f32_16x16x32_bf16(ac0, b0, g, 0, 0, 0);
      g = __builtin_amdgcn_mfma_f32_16x16x32_bf16(ac1, b1, g, 0, 0, 0);
    }
    #pragma unroll
    for (int r = 0; r < 4; r++) {
      int i = i0 + 4*lq + r, s = 16*st + l15;
      pp[st][r] = (s <= i) ? g[r] * __expf(Lc[i] - Lc[s]) * dts[s] : 0.f;
    }
  }
  __syncthreads();                                   // all waves done reading Bs
  #pragma unroll
  for (int st = 0; st < 4; st++)
    #pragma unroll
    for (int r = 0; r < 4; r++)
      BsPs[i0 + 4*lq + r][16*st + l15] = f2bf(pp[st][r]);   // P[i][s], s contiguous
  __syncthreads();
  // ---- matmul2+3: Y[i][p] = P@X + ein[i]*(C@G) + D*x ----
  short8 ap0 = *(const short8*)(&BsPs[i0 + l15][lq * 8]);
  short8 ap1 = *(const short8*)(&BsPs[i0 + l15][32 + lq * 8]);
  const float Dh = Dp[h];
  #pragma unroll
  for (int pt = 0; pt < 4; pt++) {
    const int p0 = 16 * pt;
    f32x4 y1 = (f32x4){0.f, 0.f, 0.f, 0.f};
    f32x4 y2 = (f32x4){0.f, 0.f, 0.f, 0.f};
    short8 bx0 = *(const short8*)(&Xt[p0 + l15][lq * 8]);
    y1 = __builtin_amdgcn_mfma_f32_16x16x32_bf16(ap0, bx0, y1, 0, 0, 0);
    if (w >= 2) {                                    // P rows of wave w have k < 16(w+1)
      short8 bx1 = *(const short8*)(&Xt[p0 + l15][32 + lq * 8]);
      y1 = __builtin_amdgcn_mfma_f32_16x16x32_bf16(ap1, bx1, y1, 0, 0, 0);
    }
    short8 bg0 = *(const short8*)(&Gt[p0 + l15][lq * 8]);
    short8 bg1 = *(const short8*)(&Gt[p0 + l15][32 + lq * 8]);
    y2 = __builtin_amdgcn_mfma_f32_16x16x32_bf16(ac0, bg0, y2, 0, 0, 0);
    y2 = __builtin_amdgcn_mfma_f32_16x16x32_bf16(ac1, bg1, y2, 0, 0, 0);
    #pragma unroll
    for (int r = 0; r < 4; r++) {
      int i = i0 + 4*lq + r, p = p0 + l15;
      float xv = bf2f(Xt[p][i]);
      float o = y1[r] + ein[i] * y2[r] + Dh * xv;
      Y[((size_t)(b * SEQ) + c * 64 + i) * DINNER + h * HD + p] = f2bf(o);
    }
  }
}

// ---------------- y*silu(z), RMSNorm -> bf16 -------------------------------------
__global__ __launch_bounds__(256) void k_fuse(const unsigned short* __restrict__ Y,
    const unsigned short* __restrict__ ZX, const float* __restrict__ rw,
    unsigned short* __restrict__ YN)
{
  __shared__ float red[4];
  const int row = blockIdx.x, tid = threadIdx.x;
  const unsigned short* yr = Y + (size_t)row * DINNER;
  const unsigned short* zr = ZX + (size_t)row * DINPROJ;
  float v[6]; float s2 = 0.f;
  #pragma unroll
  for (int q = 0; q < 6; q++) {
    int col = q * 256 + tid;
    float z = bf2f(zr[col]);
    float yv = bf2f(yr[col]) * (z * sigm(z));
    v[q] = yv; s2 += yv * yv;
  }
  #pragma unroll
  for (int off = 32; off; off >>= 1) s2 += __shfl_down(s2, off);
  if ((tid & 63) == 0) red[tid >> 6] = s2;
  __syncthreads();
  const float rs = rsqrtf((red[0] + red[1] + red[2] + red[3]) * (1.f / DINNER) + EPSF);
  unsigned short* yo = YN + (size_t)row * DINNER;
  #pragma unroll
  for (int q = 0; q < 6; q++) {
    int col = q * 256 + tid;
    yo[col] = f2bf(v[q] * rs * rw[col]);
  }
}

// ---------------- yg = bf16(yproj * gate), 4 elems/thread ------------------------
__global__ __launch_bounds__(256) void k_gatemul(const unsigned short* __restrict__ YP,
    const unsigned short* __restrict__ G, unsigned short* __restrict__ YG)
{
  size_t i4 = ((size_t)blockIdx.x * 256 + threadIdx.x) * 4;
  unsigned short a[4], b[4];
  *(unsigned long long*)a = *(const unsigned long long*)(YP + i4);
  *(unsigned long long*)b = *(const unsigned long long*)(G + i4);
  *(unsigned long long*)(YG + i4) = pack4bf(
      bf2f(a[0]) * bf2f(b[0]), bf2f(a[1]) * bf2f(b[1]),
      bf2f(a[2]) * bf2f(b[2]), bf2f(a[3]) * bf2f(b[3]));
}

// ---------------- launch ----------------------------------------------------------
extern "C" void kernel_launch(void* const* d_in, const int* in_sizes, int n_in,
                              void* d_out, int out_size, void* d_ws, size_t ws_size,
                              hipStream_t stream)
{
  const float* x         = (const float*)d_in[0];
  const float* ln_w      = (const float*)d_in[1];
  const float* ln_b      = (const float*)d_in[2];
  const float* in_proj_w = (const float*)d_in[3];
  const float* conv_w    = (const float*)d_in[4];
  const float* conv_b    = (const float*)d_in[5];
  const float* dt_bias   = (const float*)d_in[6];
  const float* A_log     = (const float*)d_in[7];
  const float* D_param   = (const float*)d_in[8];
  const float* rms_w     = (const float*)d_in[9];
  const float* out_proj_w= (const float*)d_in[10];
  const float* gate_w    = (const float*)d_in[11];
  const float* gate_b    = (const float*)d_in[12];
  const float* out_w     = (const float*)d_in[13];
  const float* out_b     = (const float*)d_in[14];
  float* out = (float*)d_out;
  char* ws = (char*)d_ws;

  // ---- workspace layout (bytes). peak = 177,848,320 B (~170 MB) ----
  const size_t WS_NEEDED = 177848320ull;
  if (ws_size < WS_NEEDED) return;

  unsigned short* XN    = (unsigned short*)(ws + 0);
  unsigned short* WIT   = (unsigned short*)(ws + 12582912);
  unsigned short* WGT   = (unsigned short*)(ws + 17534976);
  unsigned short* WOPT  = (unsigned short*)(ws + 18714624);
  unsigned short* WOT   = (unsigned short*)(ws + 21073920);
  unsigned short* ZXb   = (unsigned short*)(ws + 22253568);   // 8192x3224 bf16
  unsigned short* XBCCb = (unsigned short*)(ws + 75075584);   // 8192x1664 bf16
  float*          SG    = (float*)(ws + 102338560);           // 3072x4096 f32
  float*          CD    = (float*)(ws + 152670208);           // 3072 f32
  unsigned short* Yb    = (unsigned short*)(ws + 152682496);  // 8192x1536 bf16
  // overlays:
  unsigned short* YN    = (unsigned short*)(ws + 102338560);  // in SG region (dead after chunkout)
  unsigned short* Gb    = (unsigned short*)(ws + 22253568);   // in ZXb region (dead after fuse)
  unsigned short* YPb   = (unsigned short*)(ws + 34836480);   // in ZXb region
  unsigned short* YG    = (unsigned short*)(ws + 75075584);   // in XBCCb region (dead after chunkout)

  // 1) weight converts, single dispatch
  k_wtrans4<<<dim3(101, 48, 4), 256, 0, stream>>>(in_proj_w, WIT, gate_w, WGT,
                                                  out_proj_w, WOPT, out_w, WOT);
  // 2) layernorm
  k_ln<<<NTOK, 256, 0, stream>>>(x, ln_w, ln_b, XN);
  // 3) in_proj GEMM -> zxbcdt (bf16), 128x128 + XCD-aware swizzle
  k_gemm<<<dim3(26, 64), 256, 0, stream>>>(XN, WIT, nullptr, ZXb, NTOK, DINPROJ, DMODEL, 0, nullptr, nullptr);
  // 4) LDS-tiled causal conv + silu (bf16 -> bf16)
  k_conv<<<dim3(13, 128), 256, 0, stream>>>(ZXb, conv_w, conv_b, XBCCb);
  // 5-7) SSD scan
  k_chunkstate<<<dim3(NCHUNK, BSZ * NH), 256, 0, stream>>>(ZXb, XBCCb, dt_bias, A_log, SG, CD);
  k_chunkrec<<<BSZ * NH * 16, 256, 0, stream>>>(SG, CD);
  k_chunkout<<<dim3(NCHUNK, BSZ * NH), 256, 0, stream>>>(ZXb, XBCCb, SG, dt_bias, A_log, D_param, Yb);
  // 8) y*silu(z) + RMSNorm -> bf16 (YN lands in dead SG region)
  k_fuse<<<NTOK, 256, 0, stream>>>(Yb, ZXb, rms_w, YN);
  // 9+10) gate GEMM (sigmoid) + out_proj GEMM, one dispatch, bf16 outputs
  k_dualgemm<<<dim3(6, 64, 2), 256, 0, stream>>>(YN, WOPT, YPb, DINNER,
                                                 XN, WGT, Gb, DMODEL, gate_b, DMODEL);
  // 11) gate multiply -> bf16
  k_gatemul<<<(NTOK * DMODEL / 4) / 256, 256, 0, stream>>>(YPb, Gb, YG);
  // 12) final GEMM + bias + residual -> d_out
  k_gemm<<<dim3(6, 64), 256, 0, stream>>>(YG, WOT, out, nullptr, NTOK, DMODEL, DMODEL, 2, out_b, x);
}

// Round 11
// 395.882 us; speedup vs baseline: 2.0457x; 1.0375x over previous
//
#include <hip/hip_runtime.h>
#include <hip/hip_bf16.h>
#include <cstddef>

// ---------------- problem constants ----------------
#define DMODEL  768
#define DINNER  1536
#define DSTATE  64
#define NH      24
#define HD      64
#define CONVD   1664      // DINNER + 2*DSTATE
#define DINPROJ 3224      // 2*DINNER + 2*DSTATE + NH
#define SEQ     4096
#define BSZ     2
#define NTOK    8192      // BSZ*SEQ
#define NCHUNK  64        // SEQ/64
#define EPSF    1e-5f
#define LP      72        // LDS pitch (shorts) for SSD kernels
#define BUFS    8192      // 128*64 shorts per GEMM LDS buffer

typedef __attribute__((ext_vector_type(8))) short  short8;
typedef __attribute__((ext_vector_type(4))) float  f32x4;

// ---------------- helpers ----------------
__device__ __forceinline__ unsigned short f2bf(float f) {
  union { float f; unsigned int u; } v; v.f = f;
  unsigned int r = v.u + 0x7fffu + ((v.u >> 16) & 1u);   // RNE
  return (unsigned short)(r >> 16);
}
__device__ __forceinline__ float bf2f(unsigned short u) {
  union { unsigned int i; float f; } v; v.i = ((unsigned int)u) << 16; return v.f;
}
__device__ __forceinline__ unsigned long long pack4bf(float a, float b, float c, float d) {
  return (unsigned long long)(f2bf(a) | ((unsigned int)f2bf(b) << 16))
       | ((unsigned long long)(f2bf(c) | ((unsigned int)f2bf(d) << 16)) << 32);
}
__device__ __forceinline__ float sigm(float x) { return 1.f / (1.f + __expf(-x)); }

// async 16B global -> LDS (lane i of the wave lands at ldsbase + i*16)
__device__ __forceinline__ void gld16(const unsigned short* g, unsigned short* l) {
  __builtin_amdgcn_global_load_lds(
      (const __attribute__((address_space(1))) unsigned int*)g,
      (__attribute__((address_space(3))) unsigned int*)l, 16, 0, 0);
}

// XCD-aware tile remap: XCD (id&7) owns a contiguous 1/8 of the m-tiles, all n.
__device__ __forceinline__ void xcd_tiles(int& m0, int& n0) {
  const int nt = gridDim.x, mt = gridDim.y;
  const int id = blockIdx.y * nt + blockIdx.x;
  const int mper = mt >> 3;
  const int xcd = id & 7, within = id >> 3;
  m0 = (xcd * mper + (within % mper)) * 128;
  n0 = (within / mper) * 128;
}

// ---------------- LayerNorm -> bf16 ----------------
__global__ __launch_bounds__(256) void k_ln(const float* __restrict__ x,
    const float* __restrict__ w, const float* __restrict__ b,
    unsigned short* __restrict__ xn)
{
  __shared__ float red[4];
  const int row = blockIdx.x, tid = threadIdx.x;
  const float* xr = x + (size_t)row * DMODEL;
  float v[3]; float s = 0.f;
  #pragma unroll
  for (int q = 0; q < 3; q++) { v[q] = xr[q*256 + tid]; s += v[q]; }
  #pragma unroll
  for (int off = 32; off; off >>= 1) s += __shfl_down(s, off);
  if ((tid & 63) == 0) red[tid >> 6] = s;
  __syncthreads();
  const float mu = (red[0] + red[1] + red[2] + red[3]) * (1.f / DMODEL);
  __syncthreads();
  float s2 = 0.f;
  #pragma unroll
  for (int q = 0; q < 3; q++) { float d = v[q] - mu; s2 += d * d; }
  #pragma unroll
  for (int off = 32; off; off >>= 1) s2 += __shfl_down(s2, off);
  if ((tid & 63) == 0) red[tid >> 6] = s2;
  __syncthreads();
  const float rs = rsqrtf((red[0] + red[1] + red[2] + red[3]) * (1.f / DMODEL) + EPSF);
  unsigned short* xo = xn + (size_t)row * DMODEL;
  #pragma unroll
  for (int q = 0; q < 3; q++) {
    int col = q*256 + tid;
    xo[col] = f2bf((v[q] - mu) * rs * w[col] + b[col]);
  }
}

// ---------------- 4 weight transposes in one dispatch (z-indexed) ----------------
__global__ __launch_bounds__(256) void k_wtrans4(
    const float* __restrict__ W0, unsigned short* __restrict__ T0,
    const float* __restrict__ W1, unsigned short* __restrict__ T1,
    const float* __restrict__ W2, unsigned short* __restrict__ T2,
    const float* __restrict__ W3, unsigned short* __restrict__ T3)
{
  const float* W; unsigned short* T; int K, N;
  switch (blockIdx.z) {
    case 0:  W = W0; T = T0; K = 768;  N = 3224; break;
    case 1:  W = W1; T = T1; K = 768;  N = 768;  break;
    case 2:  W = W2; T = T2; K = 1536; N = 768;  break;
    default: W = W3; T = T3; K = 768;  N = 768;  break;
  }
  const int n0 = blockIdx.x * 32, k0 = blockIdx.y * 32;
  if (n0 >= N || k0 >= K) return;
  __shared__ float tile[32][33];
  const int tid = threadIdx.x;
  const int tx = tid & 31, ty = tid >> 5;           // 32 x 8
  #pragma unroll
  for (int r = 0; r < 4; r++) {
    int k = k0 + ty + 8*r;
    if (k < K && n0 + tx < N) tile[ty + 8*r][tx] = W[(size_t)k * N + n0 + tx];
  }
  __syncthreads();
  #pragma unroll
  for (int r = 0; r < 4; r++) {
    int n = n0 + ty + 8*r, k = k0 + tx;
    if (n < N && k < K) T[(size_t)n * K + k] = f2bf(tile[tx][ty + 8*r]);
  }
}

// ======== 128x128 GEMM core, BK=64, DOUBLE-BUFFERED (1 barrier/iter) =============
// Prefetch distance 1: loads(k+1) issued right after the barrier that drains
// loads(k); every load has a full compute phase in flight before it is waited.
// LDS swizzle: slot j of row r holds k-granule g = j ^ (r&7) (granule = 16B).
// epi: 0 plain, 1 sigmoid(C+bias[n]), 2 C+bias[n]+resid[m][n].  Cb!=null -> bf16 out.
__device__ __forceinline__ void gemm_core(const unsigned short* __restrict__ A,
    const unsigned short* __restrict__ Bt, float* __restrict__ C,
    unsigned short* __restrict__ Cb,
    int M, int N, int K, int epi, const float* __restrict__ bias,
    const float* __restrict__ resid, int m0, int n0,
    unsigned short* As, unsigned short* Bs)      // each 2*BUFS shorts
{
  const int tid = threadIdx.x;
  const int lane = tid & 63, w = tid >> 6;
  const int wm = (w >> 1) * 64, wn = (w & 1) * 64;
  const int l15 = lane & 15, lq = lane >> 4;
  const int sw = l15 & 7;                  // fragment-read swizzle
  f32x4 acc[4][4];
  #pragma unroll
  for (int i = 0; i < 4; i++)
    #pragma unroll
    for (int j = 0; j < 4; j++) acc[i][j] = (f32x4){0.f, 0.f, 0.f, 0.f};

  int rowg[4], gq[4], nrg[4];
  #pragma unroll
  for (int r = 0; r < 4; r++) {
    int gi = (r * 4 + w) * 64 + lane;
    rowg[r] = gi >> 3;
    gq[r] = (gi & 7) ^ (rowg[r] & 7);
    int nr = n0 + rowg[r]; if (nr >= N) nr = N - 1;   // clamp; masked in epilogue
    nrg[r] = nr;
  }

  // prologue: loads(0) -> buffer 0
  #pragma unroll
  for (int r = 0; r < 4; r++)
    gld16(A + (size_t)(m0 + rowg[r]) * K + gq[r] * 8, &As[(r * 4 + w) * 512]);
  #pragma unroll
  for (int r = 0; r < 4; r++)
    gld16(Bt + (size_t)nrg[r] * K + gq[r] * 8, &Bs[(r * 4 + w) * 512]);

  int p = 0;
  for (int k0 = 0; k0 < K; k0 += 64) {
    __syncthreads();                       // drains loads(k0); protects buf 1-p
    if (k0 + 64 < K) {
      const int pn = p ^ 1;
      #pragma unroll
      for (int r = 0; r < 4; r++)
        gld16(A + (size_t)(m0 + rowg[r]) * K + (k0 + 64) + gq[r] * 8,
              &As[pn * BUFS + (r * 4 + w) * 512]);
      #pragma unroll
      for (int r = 0; r < 4; r++)
        gld16(Bt + (size_t)nrg[r] * K + (k0 + 64) + gq[r] * 8,
              &Bs[pn * BUFS + (r * 4 + w) * 512]);
    }
    const unsigned short* Ab = As + p * BUFS;
    const unsigned short* Bb = Bs + p * BUFS;
    #pragma unroll
    for (int ks = 0; ks < 2; ks++) {
      short8 a8[4], b8[4];
      #pragma unroll
      for (int mi = 0; mi < 4; mi++)
        a8[mi] = *(const short8*)(&Ab[(wm + 16 * mi + l15) * 64 + ((lq + 4 * ks) ^ sw) * 8]);
      #pragma unroll
      for (int ni = 0; ni < 4; ni++)
        b8[ni] = *(const short8*)(&Bb[(wn + 16 * ni + l15) * 64 + ((lq + 4 * ks) ^ sw) * 8]);
      #pragma unroll
      for (int mi = 0; mi < 4; mi++)
        #pragma unroll
        for (int ni = 0; ni < 4; ni++)
          acc[mi][ni] = __builtin_amdgcn_mfma_f32_16x16x32_bf16(a8[mi], b8[ni], acc[mi][ni], 0, 0, 0);
    }
    p ^= 1;
  }
  #pragma unroll
  for (int mi = 0; mi < 4; mi++) {
    #pragma unroll
    for (int r = 0; r < 4; r++) {
      int row = m0 + wm + 16*mi + lq*4 + r;
      #pragma unroll
      for (int ni = 0; ni < 4; ni++) {
        int col = n0 + wn + 16*ni + l15;
        if (col < N) {
          float vv = acc[mi][ni][r];
          if (epi == 1)      vv = sigm(vv + bias[col]);
          else if (epi == 2) vv = vv + bias[col] + resid[(size_t)row * N + col];
          if (Cb) Cb[(size_t)row * N + col] = f2bf(vv);
          else    C [(size_t)row * N + col] = vv;
        }
      }
    }
  }
}

__global__ __launch_bounds__(256) void k_gemm(const unsigned short* __restrict__ A,
    const unsigned short* __restrict__ Bt, float* __restrict__ C,
    unsigned short* __restrict__ Cb,
    int M, int N, int K, int epi, const float* __restrict__ bias,
    const float* __restrict__ resid)
{
  __shared__ alignas(16) unsigned short As[2 * BUFS];
  __shared__ alignas(16) unsigned short Bs[2 * BUFS];
  int m0, n0;
  xcd_tiles(m0, n0);
  gemm_core(A, Bt, C, Cb, M, N, K, epi, bias, resid, m0, n0, As, Bs);
}

// two independent bf16-out GEMMs in one dispatch (z-plane):
// z=0: out_proj  YN @ WOPT -> YPb (K=1536)    z=1: gate XN @ WGT -> Gb (K=768, sigmoid)
__global__ __launch_bounds__(256) void k_dualgemm(
    const unsigned short* __restrict__ A0, const unsigned short* __restrict__ B0,
    unsigned short* __restrict__ C0, int K0,
    const unsigned short* __restrict__ A1, const unsigned short* __restrict__ B1,
    unsigned short* __restrict__ C1, int K1, const float* __restrict__ bias1, int N)
{
  __shared__ alignas(16) unsigned short As[2 * BUFS];
  __shared__ alignas(16) unsigned short Bs[2 * BUFS];
  int m0, n0;
  xcd_tiles(m0, n0);
  if (blockIdx.z == 0)
    gemm_core(A0, B0, nullptr, C0, NTOK, N, K0, 0, nullptr, nullptr, m0, n0, As, Bs);
  else
    gemm_core(A1, B1, nullptr, C1, NTOK, N, K1, 1, bias1, nullptr, m0, n0, As, Bs);
}

// ---------------- LDS-tiled causal conv1d (K=4) + SiLU ---------------------------
__global__ __launch_bounds__(256) void k_conv(const unsigned short* __restrict__ zx,
    const float* __restrict__ cw, const float* __restrict__ cb,
    unsigned short* __restrict__ out)
{
  __shared__ alignas(8) unsigned short tile[67][132];   // pitch 264 B
  const int tid = threadIdx.x;
  const int c0 = blockIdx.x * 128;          // 13 tiles x 128 = 1664 = CONVD
  const int tc = blockIdx.y;                // 128 token-chunks of 64
  const int t0 = tc * 64;
  const bool haloOK = (tc & 63) != 0;       // chunk 0 of each batch has no halo
  for (int i = tid; i < 67 * 16; i += 256) {
    int row = i >> 4, g = i & 15;
    unsigned long long v0 = 0, v1 = 0;
    if (row >= 3 || haloOK) {
      const unsigned short* p = zx + (size_t)(t0 - 3 + row) * DINPROJ + DINNER + c0 + g * 8;
      v0 = *(const unsigned long long*)p;
      v1 = *(const unsigned long long*)(p + 4);
    }
    *(unsigned long long*)(&tile[row][g * 8])     = v0;
    *(unsigned long long*)(&tile[row][g * 8 + 4]) = v1;
  }
  __syncthreads();
  const int ch0 = (tid & 63) * 2;           // 0..126
  const int trow = tid >> 6;                // 0..3
  const int cg = c0 + ch0;
  float cw0[4], cw1[4];
  #pragma unroll
  for (int k = 0; k < 4; k++) { cw0[k] = cw[cg * 4 + k]; cw1[k] = cw[(cg + 1) * 4 + k]; }
  const float cb0 = cb[cg], cb1 = cb[cg + 1];
  #pragma unroll
  for (int q = 0; q < 16; q++) {
    int tq = trow * 16 + q;
    float a0 = cb0, a1 = cb1;
    #pragma unroll
    for (int k = 0; k < 4; k++) {
      unsigned int u = *(const unsigned int*)(&tile[tq + k][ch0]);
      a0 += bf2f((unsigned short)u) * cw0[k];
      a1 += bf2f((unsigned short)(u >> 16)) * cw1[k];
    }
    float s0 = a0 * sigm(a0), s1 = a1 * sigm(a1);
    *(unsigned int*)(out + (size_t)(t0 + tq) * CONVD + cg) =
        (unsigned int)f2bf(s0) | ((unsigned int)f2bf(s1) << 16);
  }
}

// ---------------- SSD pass 1 (MFMA): S[bh,c][n][p] = sum_s (B[s][n]*wv[s]) X[s][p]
__global__ __launch_bounds__(256) void k_chunkstate(const unsigned short* __restrict__ zx,
    const unsigned short* __restrict__ xbcc, const float* __restrict__ dt_bias,
    const float* __restrict__ A_log, float* __restrict__ S, float* __restrict__ CD)
{
  const int c = blockIdx.x, bh = blockIdx.y;
  const int b = bh / NH, h = bh % NH;
  const int tid = threadIdx.x;
  const int lane = tid & 63, w = tid >> 6;
  const int l15 = lane & 15, lq = lane >> 4;
  __shared__ float wv_[64];
  __shared__ alignas(16) unsigned short Bwt[64][LP];  // [n][s]
  __shared__ alignas(16) unsigned short Xt [64][LP];  // [p][s]

  if (tid < 64) {                     // wave 0: dt, prefix-scan of Lc
    int t = c * 64 + tid;
    float xx = bf2f(zx[((size_t)(b * SEQ + t)) * DINPROJ + (DINNER + CONVD) + h]) + dt_bias[h];
    float dt_ = (xx > 15.f) ? xx : log1pf(__expf(xx));
    float Ah = -__expf(A_log[h]);
    float v = dt_ * Ah;
    #pragma unroll
    for (int off = 1; off < 64; off <<= 1) {
      float u = __shfl_up(v, off);
      if (tid >= off) v += u;
    }
    float L63 = __shfl(v, 63);
    wv_[tid] = __expf(L63 - v) * dt_;
    if (tid == 63) CD[bh * 64 + c] = __expf(v);
  }
  unsigned long long braw[4];
  #pragma unroll
  for (int it = 0; it < 4; it++) {
    int i4 = tid + 256 * it;
    int s = i4 >> 4, q4 = (i4 & 15) * 4;
    size_t rb = ((size_t)(b * SEQ) + c * 64 + s) * CONVD;
    braw[it] = *(const unsigned long long*)(xbcc + rb + DINNER + q4);
    unsigned short xs[4];
    *(unsigned long long*)xs = *(const unsigned long long*)(xbcc + rb + h * HD + q4);
    Xt[q4+0][s] = xs[0]; Xt[q4+1][s] = xs[1]; Xt[q4+2][s] = xs[2]; Xt[q4+3][s] = xs[3];
  }
  __syncthreads();
  #pragma unroll
  for (int it = 0; it < 4; it++) {
    int i4 = tid + 256 * it;
    int s = i4 >> 4, q4 = (i4 & 15) * 4;
    float wsc = wv_[s];
    unsigned short us[4];
    *(unsigned long long*)us = braw[it];
    Bwt[q4+0][s] = f2bf(bf2f(us[0]) * wsc);
    Bwt[q4+1][s] = f2bf(bf2f(us[1]) * wsc);
    Bwt[q4+2][s] = f2bf(bf2f(us[2]) * wsc);
    Bwt[q4+3][s] = f2bf(bf2f(us[3]) * wsc);
  }
  __syncthreads();
  const int n0 = 16 * w;
  short8 a0 = *(const short8*)(&Bwt[n0 + l15][lq * 8]);
  short8 a1 = *(const short8*)(&Bwt[n0 + l15][32 + lq * 8]);
  size_t sb = ((size_t)bh * 64 + c) * 4096;
  #pragma unroll
  for (int pt = 0; pt < 4; pt++) {
    f32x4 acc = (f32x4){0.f, 0.f, 0.f, 0.f};
    short8 b0 = *(const short8*)(&Xt[16*pt + l15][lq * 8]);
    short8 b1 = *(const short8*)(&Xt[16*pt + l15][32 + lq * 8]);
    acc = __builtin_amdgcn_mfma_f32_16x16x32_bf16(a0, b0, acc, 0, 0, 0);
    acc = __builtin_amdgcn_mfma_f32_16x16x32_bf16(a1, b1, acc, 0, 0, 0);
    #pragma unroll
    for (int r = 0; r < 4; r++) {
      int n = n0 + 4*lq + r, p = 16*pt + l15;
      S[sb + (size_t)n * 64 + p] = acc[r];
    }
  }
}

// ---------------- SSD pass 2: chunk-level recurrence (in-place S -> G) -----------
__global__ __launch_bounds__(256) void k_chunkrec(float* __restrict__ S,
    const float* __restrict__ CD)
{
  const int bh = blockIdx.x >> 4, part = blockIdx.x & 15;
  const int e = part * 256 + threadIdx.x;
  float g = 0.f;
  size_t base = (size_t)bh * 64 * 4096 + e;
  for (int c = 0; c < 64; c++) {
    size_t ad = base + (size_t)c * 4096;
    float sv = S[ad];
    float pc = CD[bh * 64 + c];
    S[ad] = g;               // slot c now holds G_c (state before chunk c)
    g = pc * g + sv;
  }
}

// ---------------- SSD pass 3 (MFMA): per-chunk outputs (bf16 Y out) --------------
__global__ __launch_bounds__(256) void k_chunkout(const unsigned short* __restrict__ zx,
    const unsigned short* __restrict__ xbcc, const float* __restrict__ S,
    const float* __restrict__ dt_bias, const float* __restrict__ A_log,
    const float* __restrict__ Dp, unsigned short* __restrict__ Y)
{
  const int c = blockIdx.x, bh = blockIdx.y;
  const int b = bh / NH, h = bh % NH;
  const int tid = threadIdx.x;
  const int lane = tid & 63, w = tid >> 6;
  const int l15 = lane & 15, lq = lane >> 4;
  __shared__ float dts[64], Lc[64], ein[64];
  __shared__ alignas(16) unsigned short Cs  [64][LP];  // [i][n]
  __shared__ alignas(16) unsigned short BsPs[64][LP];  // [s][n], then P[i][s]
  __shared__ alignas(16) unsigned short Xt  [64][LP];  // [p][s]
  __shared__ alignas(16) unsigned short Gt  [64][LP];  // [p][n]

  if (tid < 64) {                     // wave 0: dt, prefix-scan of Lc
    int t = c * 64 + tid;
    float xx = bf2f(zx[((size_t)(b * SEQ + t)) * DINPROJ + (DINNER + CONVD) + h]) + dt_bias[h];
    float dt_ = (xx > 15.f) ? xx : log1pf(__expf(xx));
    dts[tid] = dt_;
    float Ah = -__expf(A_log[h]);
    float v = dt_ * Ah;
    #pragma unroll
    for (int off = 1; off < 64; off <<= 1) {
      float u = __shfl_up(v, off);
      if (tid >= off) v += u;
    }
    Lc[tid] = v;
    ein[tid] = __expf(v);
  }
  const size_t gslot = ((size_t)bh * 64 + c) * 4096;
  #pragma unroll
  for (int it = 0; it < 4; it++) {
    int i4 = tid + 256 * it;
    int rr = i4 >> 4, q4 = (i4 & 15) * 4;
    size_t rb = ((size_t)(b * SEQ) + c * 64 + rr) * CONVD;
    const unsigned short* pC = xbcc + rb + (DINNER + DSTATE) + q4;
    Cs[rr][q4+0] = pC[0]; Cs[rr][q4+1] = pC[1]; Cs[rr][q4+2] = pC[2]; Cs[rr][q4+3] = pC[3];
    const unsigned short* pB = xbcc + rb + DINNER + q4;
    BsPs[rr][q4+0] = pB[0]; BsPs[rr][q4+1] = pB[1]; BsPs[rr][q4+2] = pB[2]; BsPs[rr][q4+3] = pB[3];
    unsigned short xs[4];
    *(unsigned long long*)xs = *(const unsigned long long*)(xbcc + rb + h * HD + q4);
    Xt[q4+0][rr] = xs[0]; Xt[q4+1][rr] = xs[1]; Xt[q4+2][rr] = xs[2]; Xt[q4+3][rr] = xs[3];
    float4 vG = *(const float4*)(S + gslot + (size_t)i4 * 4);   // row n=rr, cols q4..q4+3
    Gt[q4+0][rr] = f2bf(vG.x); Gt[q4+1][rr] = f2bf(vG.y);
    Gt[q4+2][rr] = f2bf(vG.z); Gt[q4+3][rr] = f2bf(vG.w);
  }
  __syncthreads();
  // ---- matmul1: G[i][s] = sum_n C[i][n] B[s][n]; apply causal decay mask -> P ----
  const int i0 = 16 * w;
  short8 ac0 = *(const short8*)(&Cs[i0 + l15][lq * 8]);
  short8 ac1 = *(const short8*)(&Cs[i0 + l15][32 + lq * 8]);
  float pp[4][4];
  #pragma unroll
  for (int st = 0; st < 4; st++) {
    f32x4 g = (f32x4){0.f, 0.f, 0.f, 0.f};
    if (st <= w) {                                   // wave-uniform causal skip
      short8 b0 = *(const short8*)(&BsPs[16*st + l15][lq * 8]);
      short8 b1 = *(const short8*)(&BsPs[16*st + l15][32 + lq * 8]);
      g = __builtin_amdgcn_mfma_f32_16x16x32_bf16(ac0, b0, g, 0, 0, 0);
      g = __builtin_amdgcn_mfma_f32_16x16x32_bf16(ac1, b1, g, 0, 0, 0);
    }
    #pragma unroll
    for (int r = 0; r < 4; r++) {
      int i = i0 + 4*lq + r, s = 16*st + l15;
      pp[st][r] = (s <= i) ? g[r] * __expf(Lc[i] - Lc[s]) * dts[s] : 0.f;
    }
  }
  __syncthreads();                                   // all waves done reading Bs
  #pragma unroll
  for (int st = 0; st < 4; st++)
    #pragma unroll
    for (int r = 0; r < 4; r++)
      BsPs[i0 + 4*lq + r][16*st + l15] = f2bf(pp[st][r]);   // P[i][s], s contiguous
  __syncthreads();
  // ---- matmul2+3: Y[i][p] = P@X + ein[i]*(C@G) + D*x ----
  short8 ap0 = *(const short8*)(&BsPs[i0 + l15][lq * 8]);
  short8 ap1 = *(const short8*)(&BsPs[i0 + l15][32 + lq * 8]);
  const float Dh = Dp[h];
  #pragma unroll
  for (int pt = 0; pt < 4; pt++) {
    const int p0 = 16 * pt;
    f32x4 y1 = (f32x4){0.f, 0.f, 0.f, 0.f};
    f32x4 y2 = (f32x4){0.f, 0.f, 0.f, 0.f};
    short8 bx0 = *(const short8*)(&Xt[p0 + l15][lq * 8]);
    y1 = __builtin_amdgcn_mfma_f32_16x16x32_bf16(ap0, bx0, y1, 0, 0, 0);
    if (w >= 2) {                                    // P rows of wave w have k < 16(w+1)
      short8 bx1 = *(const short8*)(&Xt[p0 + l15][32 + lq * 8]);
      y1 = __builtin_amdgcn_mfma_f32_16x16x32_bf16(ap1, bx1, y1, 0, 0, 0);
    }
    short8 bg0 = *(const short8*)(&Gt[p0 + l15][lq * 8]);
    short8 bg1 = *(const short8*)(&Gt[p0 + l15][32 + lq * 8]);
    y2 = __builtin_amdgcn_mfma_f32_16x16x32_bf16(ac0, bg0, y2, 0, 0, 0);
    y2 = __builtin_amdgcn_mfma_f32_16x16x32_bf16(ac1, bg1, y2, 0, 0, 0);
    #pragma unroll
    for (int r = 0; r < 4; r++) {
      int i = i0 + 4*lq + r, p = p0 + l15;
      float xv = bf2f(Xt[p][i]);
      float o = y1[r] + ein[i] * y2[r] + Dh * xv;
      Y[((size_t)(b * SEQ) + c * 64 + i) * DINNER + h * HD + p] = f2bf(o);
    }
  }
}

// ---------------- y*silu(z), RMSNorm -> bf16 -------------------------------------
__global__ __launch_bounds__(256) void k_fuse(const unsigned short* __restrict__ Y,
    const unsigned short* __restrict__ ZX, const float* __restrict__ rw,
    unsigned short* __restrict__ YN)
{
  __shared__ float red[4];
  const int row = blockIdx.x, tid = threadIdx.x;
  const unsigned short* yr = Y + (size_t)row * DINNER;
  const unsigned short* zr = ZX + (size_t)row * DINPROJ;
  float v[6]; float s2 = 0.f;
  #pragma unroll
  for (int q = 0; q < 6; q++) {
    int col = q * 256 + tid;
    float z = bf2f(zr[col]);
    float yv = bf2f(yr[col]) * (z * sigm(z));
    v[q] = yv; s2 += yv * yv;
  }
  #pragma unroll
  for (int off = 32; off; off >>= 1) s2 += __shfl_down(s2, off);
  if ((tid & 63) == 0) red[tid >> 6] = s2;
  __syncthreads();
  const float rs = rsqrtf((red[0] + red[1] + red[2] + red[3]) * (1.f / DINNER) + EPSF);
  unsigned short* yo = YN + (size_t)row * DINNER;
  #pragma unroll
  for (int q = 0; q < 6; q++) {
    int col = q * 256 + tid;
    yo[col] = f2bf(v[q] * rs * rw[col]);
  }
}

// ---------------- yg = bf16(yproj * gate), 4 elems/thread ------------------------
__global__ __launch_bounds__(256) void k_gatemul(const unsigned short* __restrict__ YP,
    const unsigned short* __restrict__ G, unsigned short* __restrict__ YG)
{
  size_t i4 = ((size_t)blockIdx.x * 256 + threadIdx.x) * 4;
  unsigned short a[4], b[4];
  *(unsigned long long*)a = *(const unsigned long long*)(YP + i4);
  *(unsigned long long*)b = *(const unsigned long long*)(G + i4);
  *(unsigned long long*)(YG + i4) = pack4bf(
      bf2f(a[0]) * bf2f(b[0]), bf2f(a[1]) * bf2f(b[1]),
      bf2f(a[2]) * bf2f(b[2]), bf2f(a[3]) * bf2f(b[3]));
}

// ---------------- launch ----------------------------------------------------------
extern "C" void kernel_launch(void* const* d_in, const int* in_sizes, int n_in,
                              void* d_out, int out_size, void* d_ws, size_t ws_size,
                              hipStream_t stream)
{
  const float* x         = (const float*)d_in[0];
  const float* ln_w      = (const float*)d_in[1];
  const float* ln_b      = (const float*)d_in[2];
  const float* in_proj_w = (const float*)d_in[3];
  const float* conv_w    = (const float*)d_in[4];
  const float* conv_b    = (const float*)d_in[5];
  const float* dt_bias   = (const float*)d_in[6];
  const float* A_log     = (const float*)d_in[7];
  const float* D_param   = (const float*)d_in[8];
  const float* rms_w     = (const float*)d_in[9];
  const float* out_proj_w= (const float*)d_in[10];
  const float* gate_w    = (const float*)d_in[11];
  const float* gate_b    = (const float*)d_in[12];
  const float* out_w     = (const float*)d_in[13];
  const float* out_b     = (const float*)d_in[14];
  float* out = (float*)d_out;
  char* ws = (char*)d_ws;

  // ---- workspace layout (bytes). peak = 177,848,320 B (~170 MB) ----
  const size_t WS_NEEDED = 177848320ull;
  if (ws_size < WS_NEEDED) return;

  unsigned short* XN    = (unsigned short*)(ws + 0);
  unsigned short* WIT   = (unsigned short*)(ws + 12582912);
  unsigned short* WGT   = (unsigned short*)(ws + 17534976);
  unsigned short* WOPT  = (unsigned short*)(ws + 18714624);
  unsigned short* WOT   = (unsigned short*)(ws + 21073920);
  unsigned short* ZXb   = (unsigned short*)(ws + 22253568);   // 8192x3224 bf16
  unsigned short* XBCCb = (unsigned short*)(ws + 75075584);   // 8192x1664 bf16
  float*          SG    = (float*)(ws + 102338560);           // 3072x4096 f32
  float*          CD    = (float*)(ws + 152670208);           // 3072 f32
  unsigned short* Yb    = (unsigned short*)(ws + 152682496);  // 8192x1536 bf16
  // overlays:
  unsigned short* YN    = (unsigned short*)(ws + 102338560);  // in SG region (dead after chunkout)
  unsigned short* Gb    = (unsigned short*)(ws + 22253568);   // in ZXb region (dead after fuse)
  unsigned short* YPb   = (unsigned short*)(ws + 34836480);   // in ZXb region
  unsigned short* YG    = (unsigned short*)(ws + 75075584);   // in XBCCb region (dead after chunkout)

  // 1) weight converts, single dispatch
  k_wtrans4<<<dim3(101, 48, 4), 256, 0, stream>>>(in_proj_w, WIT, gate_w, WGT,
                                                  out_proj_w, WOPT, out_w, WOT);
  // 2) layernorm
  k_ln<<<NTOK, 256, 0, stream>>>(x, ln_w, ln_b, XN);
  // 3) in_proj GEMM -> zxbcdt (bf16), dbuf + XCD swizzle
  k_gemm<<<dim3(26, 64), 256, 0, stream>>>(XN, WIT, nullptr, ZXb, NTOK, DINPROJ, DMODEL, 0, nullptr, nullptr);
  // 4) LDS-tiled causal conv + silu (bf16 -> bf16)
  k_conv<<<dim3(13, 128), 256, 0, stream>>>(ZXb, conv_w, conv_b, XBCCb);
  // 5-7) SSD scan
  k_chunkstate<<<dim3(NCHUNK, BSZ * NH), 256, 0, stream>>>(ZXb, XBCCb, dt_bias, A_log, SG, CD);
  k_chunkrec<<<BSZ * NH * 16, 256, 0, stream>>>(SG, CD);
  k_chunkout<<<dim3(NCHUNK, BSZ * NH), 256, 0, stream>>>(ZXb, XBCCb, SG, dt_bias, A_log, D_param, Yb);
  // 8) y*silu(z) + RMSNorm -> bf16 (YN lands in dead SG region)
  k_fuse<<<NTOK, 256, 0, stream>>>(Yb, ZXb, rms_w, YN);
  // 9+10) gate GEMM (sigmoid) + out_proj GEMM, one dispatch, bf16 outputs
  k_dualgemm<<<dim3(6, 64, 2), 256, 0, stream>>>(YN, WOPT, YPb, DINNER,
                                                 XN, WGT, Gb, DMODEL, gate_b, DMODEL);
  // 11) gate multiply -> bf16
  k_gatemul<<<(NTOK * DMODEL / 4) / 256, 256, 0, stream>>>(YPb, Gb, YG);
  // 12) final GEMM + bias + residual -> d_out
  k_gemm<<<dim3(6, 64), 256, 0, stream>>>(YG, WOT, out, nullptr, NTOK, DMODEL, DMODEL, 2, out_b, x);
}

// Round 12
// 367.894 us; speedup vs baseline: 2.2013x; 1.0761x over previous
//
#include <hip/hip_runtime.h>
#include <hip/hip_bf16.h>
#include <cstddef>

// ---------------- problem constants ----------------
#define DMODEL  768
#define DINNER  1536
#define DSTATE  64
#define NH      24
#define HD      64
#define CONVD   1664      // DINNER + 2*DSTATE
#define DINPROJ 3224      // 2*DINNER + 2*DSTATE + NH
#define SEQ     4096
#define BSZ     2
#define NTOK    8192      // BSZ*SEQ
#define NCHUNK  64        // SEQ/64
#define EPSF    1e-5f
#define LP      72        // LDS pitch (shorts) for SSD kernels
#define BUFS    8192      // 128*64 shorts per GEMM LDS buffer

typedef __attribute__((ext_vector_type(8))) short  short8;
typedef __attribute__((ext_vector_type(4))) float  f32x4;

// ---------------- helpers ----------------
__device__ __forceinline__ unsigned short f2bf(float f) {
  union { float f; unsigned int u; } v; v.f = f;
  unsigned int r = v.u + 0x7fffu + ((v.u >> 16) & 1u);   // RNE
  return (unsigned short)(r >> 16);
}
__device__ __forceinline__ float bf2f(unsigned short u) {
  union { unsigned int i; float f; } v; v.i = ((unsigned int)u) << 16; return v.f;
}
__device__ __forceinline__ unsigned long long pack4bf(float a, float b, float c, float d) {
  return (unsigned long long)(f2bf(a) | ((unsigned int)f2bf(b) << 16))
       | ((unsigned long long)(f2bf(c) | ((unsigned int)f2bf(d) << 16)) << 32);
}
__device__ __forceinline__ float sigm(float x) { return 1.f / (1.f + __expf(-x)); }

// async 16B global -> LDS (lane i of the wave lands at ldsbase + i*16)
__device__ __forceinline__ void gld16(const unsigned short* g, unsigned short* l) {
  __builtin_amdgcn_global_load_lds(
      (const __attribute__((address_space(1))) unsigned int*)g,
      (__attribute__((address_space(3))) unsigned int*)l, 16, 0, 0);
}

// XCD-aware tile remap for 2D grids: XCD (id&7) owns a contiguous 1/8 of m-tiles.
__device__ __forceinline__ void xcd_tiles(int& m0, int& n0) {
  const int nt = gridDim.x, mt = gridDim.y;
  const int id = blockIdx.y * nt + blockIdx.x;
  const int mper = mt >> 3;
  const int xcd = id & 7, within = id >> 3;
  m0 = (xcd * mper + (within % mper)) * 128;
  n0 = (within / mper) * 128;
}

// ---------------- LayerNorm -> bf16 ----------------
__global__ __launch_bounds__(256) void k_ln(const float* __restrict__ x,
    const float* __restrict__ w, const float* __restrict__ b,
    unsigned short* __restrict__ xn)
{
  __shared__ float red[4];
  const int row = blockIdx.x, tid = threadIdx.x;
  const float* xr = x + (size_t)row * DMODEL;
  float v[3]; float s = 0.f;
  #pragma unroll
  for (int q = 0; q < 3; q++) { v[q] = xr[q*256 + tid]; s += v[q]; }
  #pragma unroll
  for (int off = 32; off; off >>= 1) s += __shfl_down(s, off);
  if ((tid & 63) == 0) red[tid >> 6] = s;
  __syncthreads();
  const float mu = (red[0] + red[1] + red[2] + red[3]) * (1.f / DMODEL);
  __syncthreads();
  float s2 = 0.f;
  #pragma unroll
  for (int q = 0; q < 3; q++) { float d = v[q] - mu; s2 += d * d; }
  #pragma unroll
  for (int off = 32; off; off >>= 1) s2 += __shfl_down(s2, off);
  if ((tid & 63) == 0) red[tid >> 6] = s2;
  __syncthreads();
  const float rs = rsqrtf((red[0] + red[1] + red[2] + red[3]) * (1.f / DMODEL) + EPSF);
  unsigned short* xo = xn + (size_t)row * DMODEL;
  #pragma unroll
  for (int q = 0; q < 3; q++) {
    int col = q*256 + tid;
    xo[col] = f2bf((v[q] - mu) * rs * w[col] + b[col]);
  }
}

// ---------------- 4 weight transposes in one dispatch (z-indexed) ----------------
__global__ __launch_bounds__(256) void k_wtrans4(
    const float* __restrict__ W0, unsigned short* __restrict__ T0,
    const float* __restrict__ W1, unsigned short* __restrict__ T1,
    const float* __restrict__ W2, unsigned short* __restrict__ T2,
    const float* __restrict__ W3, unsigned short* __restrict__ T3)
{
  const float* W; unsigned short* T; int K, N;
  switch (blockIdx.z) {
    case 0:  W = W0; T = T0; K = 768;  N = 3224; break;
    case 1:  W = W1; T = T1; K = 768;  N = 768;  break;
    case 2:  W = W2; T = T2; K = 1536; N = 768;  break;
    default: W = W3; T = T3; K = 768;  N = 768;  break;
  }
  const int n0 = blockIdx.x * 32, k0 = blockIdx.y * 32;
  if (n0 >= N || k0 >= K) return;
  __shared__ float tile[32][33];
  const int tid = threadIdx.x;
  const int tx = tid & 31, ty = tid >> 5;           // 32 x 8
  #pragma unroll
  for (int r = 0; r < 4; r++) {
    int k = k0 + ty + 8*r;
    if (k < K && n0 + tx < N) tile[ty + 8*r][tx] = W[(size_t)k * N + n0 + tx];
  }
  __syncthreads();
  #pragma unroll
  for (int r = 0; r < 4; r++) {
    int n = n0 + ty + 8*r, k = k0 + tx;
    if (n < N && k < K) T[(size_t)n * K + k] = f2bf(tile[tx][ty + 8*r]);
  }
}

// ======== 128x128 GEMM core, BK=64, DOUBLE-BUFFERED (1 barrier/iter) =============
// Prefetch distance 1; LDS swizzle: slot j of row r holds k-granule j ^ (r&7).
// epi: 0 plain, 1 sigmoid(C+bias[n]), 2 C+bias[n]+resid[m][n].  Cb!=null -> bf16 out.
__device__ __forceinline__ void gemm_core(const unsigned short* __restrict__ A,
    const unsigned short* __restrict__ Bt, float* __restrict__ C,
    unsigned short* __restrict__ Cb,
    int M, int N, int K, int epi, const float* __restrict__ bias,
    const float* __restrict__ resid, int m0, int n0,
    unsigned short* As, unsigned short* Bs)      // each 2*BUFS shorts
{
  const int tid = threadIdx.x;
  const int lane = tid & 63, w = tid >> 6;
  const int wm = (w >> 1) * 64, wn = (w & 1) * 64;
  const int l15 = lane & 15, lq = lane >> 4;
  const int sw = l15 & 7;                  // fragment-read swizzle
  f32x4 acc[4][4];
  #pragma unroll
  for (int i = 0; i < 4; i++)
    #pragma unroll
    for (int j = 0; j < 4; j++) acc[i][j] = (f32x4){0.f, 0.f, 0.f, 0.f};

  int rowg[4], gq[4], nrg[4];
  #pragma unroll
  for (int r = 0; r < 4; r++) {
    int gi = (r * 4 + w) * 64 + lane;
    rowg[r] = gi >> 3;
    gq[r] = (gi & 7) ^ (rowg[r] & 7);
    int nr = n0 + rowg[r]; if (nr >= N) nr = N - 1;   // clamp; masked in epilogue
    nrg[r] = nr;
  }

  // prologue: loads(0) -> buffer 0
  #pragma unroll
  for (int r = 0; r < 4; r++)
    gld16(A + (size_t)(m0 + rowg[r]) * K + gq[r] * 8, &As[(r * 4 + w) * 512]);
  #pragma unroll
  for (int r = 0; r < 4; r++)
    gld16(Bt + (size_t)nrg[r] * K + gq[r] * 8, &Bs[(r * 4 + w) * 512]);

  int p = 0;
  for (int k0 = 0; k0 < K; k0 += 64) {
    __syncthreads();                       // drains loads(k0); protects buf 1-p
    if (k0 + 64 < K) {
      const int pn = p ^ 1;
      #pragma unroll
      for (int r = 0; r < 4; r++)
        gld16(A + (size_t)(m0 + rowg[r]) * K + (k0 + 64) + gq[r] * 8,
              &As[pn * BUFS + (r * 4 + w) * 512]);
      #pragma unroll
      for (int r = 0; r < 4; r++)
        gld16(Bt + (size_t)nrg[r] * K + (k0 + 64) + gq[r] * 8,
              &Bs[pn * BUFS + (r * 4 + w) * 512]);
    }
    const unsigned short* Ab = As + p * BUFS;
    const unsigned short* Bb = Bs + p * BUFS;
    #pragma unroll
    for (int ks = 0; ks < 2; ks++) {
      short8 a8[4], b8[4];
      #pragma unroll
      for (int mi = 0; mi < 4; mi++)
        a8[mi] = *(const short8*)(&Ab[(wm + 16 * mi + l15) * 64 + ((lq + 4 * ks) ^ sw) * 8]);
      #pragma unroll
      for (int ni = 0; ni < 4; ni++)
        b8[ni] = *(const short8*)(&Bb[(wn + 16 * ni + l15) * 64 + ((lq + 4 * ks) ^ sw) * 8]);
      #pragma unroll
      for (int mi = 0; mi < 4; mi++)
        #pragma unroll
        for (int ni = 0; ni < 4; ni++)
          acc[mi][ni] = __builtin_amdgcn_mfma_f32_16x16x32_bf16(a8[mi], b8[ni], acc[mi][ni], 0, 0, 0);
    }
    p ^= 1;
  }
  #pragma unroll
  for (int mi = 0; mi < 4; mi++) {
    #pragma unroll
    for (int r = 0; r < 4; r++) {
      int row = m0 + wm + 16*mi + lq*4 + r;
      #pragma unroll
      for (int ni = 0; ni < 4; ni++) {
        int col = n0 + wn + 16*ni + l15;
        if (col < N) {
          float vv = acc[mi][ni][r];
          if (epi == 1)      vv = sigm(vv + bias[col]);
          else if (epi == 2) vv = vv + bias[col] + resid[(size_t)row * N + col];
          if (Cb) Cb[(size_t)row * N + col] = f2bf(vv);
          else    C [(size_t)row * N + col] = vv;
        }
      }
    }
  }
}

__global__ __launch_bounds__(256) void k_gemm(const unsigned short* __restrict__ A,
    const unsigned short* __restrict__ Bt, float* __restrict__ C,
    unsigned short* __restrict__ Cb,
    int M, int N, int K, int epi, const float* __restrict__ bias,
    const float* __restrict__ resid)
{
  __shared__ alignas(16) unsigned short As[2 * BUFS];
  __shared__ alignas(16) unsigned short Bs[2 * BUFS];
  int m0, n0;
  xcd_tiles(m0, n0);
  gemm_core(A, Bt, C, Cb, M, N, K, epi, bias, resid, m0, n0, As, Bs);
}

// in_proj + gate in ONE dispatch: 2048 blocks = exactly 4 occupancy rounds.
// Per XCD (id&7): 256 blocks = 208 in_proj tiles (26n x 8m) + 48 gate (6n x 8m).
__global__ __launch_bounds__(256) void k_ipg(
    const unsigned short* __restrict__ XN, const unsigned short* __restrict__ WIT,
    unsigned short* __restrict__ ZXb,
    const unsigned short* __restrict__ WGT, unsigned short* __restrict__ Gb,
    const float* __restrict__ gate_b)
{
  __shared__ alignas(16) unsigned short As[2 * BUFS];
  __shared__ alignas(16) unsigned short Bs[2 * BUFS];
  const int id = blockIdx.x;
  const int xcd = id & 7, within = id >> 3;
  if (within < 208) {
    int m0 = (xcd * 8 + (within & 7)) * 128;
    int n0 = (within >> 3) * 128;
    gemm_core(XN, WIT, nullptr, ZXb, NTOK, DINPROJ, DMODEL, 0, nullptr, nullptr, m0, n0, As, Bs);
  } else {
    int w2 = within - 208;
    int m0 = (xcd * 8 + (w2 & 7)) * 128;
    int n0 = (w2 >> 3) * 128;
    gemm_core(XN, WGT, nullptr, Gb, NTOK, DMODEL, DMODEL, 1, gate_b, nullptr, m0, n0, As, Bs);
  }
}

// ---------------- LDS-tiled causal conv1d (K=4) + SiLU ---------------------------
__global__ __launch_bounds__(256) void k_conv(const unsigned short* __restrict__ zx,
    const float* __restrict__ cw, const float* __restrict__ cb,
    unsigned short* __restrict__ out)
{
  __shared__ alignas(8) unsigned short tile[67][132];   // pitch 264 B
  const int tid = threadIdx.x;
  const int c0 = blockIdx.x * 128;          // 13 tiles x 128 = 1664 = CONVD
  const int tc = blockIdx.y;                // 128 token-chunks of 64
  const int t0 = tc * 64;
  const bool haloOK = (tc & 63) != 0;       // chunk 0 of each batch has no halo
  for (int i = tid; i < 67 * 16; i += 256) {
    int row = i >> 4, g = i & 15;
    unsigned long long v0 = 0, v1 = 0;
    if (row >= 3 || haloOK) {
      const unsigned short* p = zx + (size_t)(t0 - 3 + row) * DINPROJ + DINNER + c0 + g * 8;
      v0 = *(const unsigned long long*)p;
      v1 = *(const unsigned long long*)(p + 4);
    }
    *(unsigned long long*)(&tile[row][g * 8])     = v0;
    *(unsigned long long*)(&tile[row][g * 8 + 4]) = v1;
  }
  __syncthreads();
  const int ch0 = (tid & 63) * 2;           // 0..126
  const int trow = tid >> 6;                // 0..3
  const int cg = c0 + ch0;
  float cw0[4], cw1[4];
  #pragma unroll
  for (int k = 0; k < 4; k++) { cw0[k] = cw[cg * 4 + k]; cw1[k] = cw[(cg + 1) * 4 + k]; }
  const float cb0 = cb[cg], cb1 = cb[cg + 1];
  #pragma unroll
  for (int q = 0; q < 16; q++) {
    int tq = trow * 16 + q;
    float a0 = cb0, a1 = cb1;
    #pragma unroll
    for (int k = 0; k < 4; k++) {
      unsigned int u = *(const unsigned int*)(&tile[tq + k][ch0]);
      a0 += bf2f((unsigned short)u) * cw0[k];
      a1 += bf2f((unsigned short)(u >> 16)) * cw1[k];
    }
    float s0 = a0 * sigm(a0), s1 = a1 * sigm(a1);
    *(unsigned int*)(out + (size_t)(t0 + tq) * CONVD + cg) =
        (unsigned int)f2bf(s0) | ((unsigned int)f2bf(s1) << 16);
  }
}

// ---------------- SSD pass 1 (MFMA): S[bh,c][n][p] (bf16) ------------------------
__global__ __launch_bounds__(256) void k_chunkstate(const unsigned short* __restrict__ zx,
    const unsigned short* __restrict__ xbcc, const float* __restrict__ dt_bias,
    const float* __restrict__ A_log, unsigned short* __restrict__ S, float* __restrict__ CD)
{
  const int c = blockIdx.x, bh = blockIdx.y;
  const int b = bh / NH, h = bh % NH;
  const int tid = threadIdx.x;
  const int lane = tid & 63, w = tid >> 6;
  const int l15 = lane & 15, lq = lane >> 4;
  __shared__ float wv_[64];
  __shared__ alignas(16) unsigned short Bwt[64][LP];  // [n][s]
  __shared__ alignas(16) unsigned short Xt [64][LP];  // [p][s]

  if (tid < 64) {                     // wave 0: dt, prefix-scan of Lc
    int t = c * 64 + tid;
    float xx = bf2f(zx[((size_t)(b * SEQ + t)) * DINPROJ + (DINNER + CONVD) + h]) + dt_bias[h];
    float dt_ = (xx > 15.f) ? xx : log1pf(__expf(xx));
    float Ah = -__expf(A_log[h]);
    float v = dt_ * Ah;
    #pragma unroll
    for (int off = 1; off < 64; off <<= 1) {
      float u = __shfl_up(v, off);
      if (tid >= off) v += u;
    }
    float L63 = __shfl(v, 63);
    wv_[tid] = __expf(L63 - v) * dt_;
    if (tid == 63) CD[bh * 64 + c] = __expf(v);
  }
  unsigned long long braw[4];
  #pragma unroll
  for (int it = 0; it < 4; it++) {
    int i4 = tid + 256 * it;
    int s = i4 >> 4, q4 = (i4 & 15) * 4;
    size_t rb = ((size_t)(b * SEQ) + c * 64 + s) * CONVD;
    braw[it] = *(const unsigned long long*)(xbcc + rb + DINNER + q4);
    unsigned short xs[4];
    *(unsigned long long*)xs = *(const unsigned long long*)(xbcc + rb + h * HD + q4);
    Xt[q4+0][s] = xs[0]; Xt[q4+1][s] = xs[1]; Xt[q4+2][s] = xs[2]; Xt[q4+3][s] = xs[3];
  }
  __syncthreads();
  #pragma unroll
  for (int it = 0; it < 4; it++) {
    int i4 = tid + 256 * it;
    int s = i4 >> 4, q4 = (i4 & 15) * 4;
    float wsc = wv_[s];
    unsigned short us[4];
    *(unsigned long long*)us = braw[it];
    Bwt[q4+0][s] = f2bf(bf2f(us[0]) * wsc);
    Bwt[q4+1][s] = f2bf(bf2f(us[1]) * wsc);
    Bwt[q4+2][s] = f2bf(bf2f(us[2]) * wsc);
    Bwt[q4+3][s] = f2bf(bf2f(us[3]) * wsc);
  }
  __syncthreads();
  const int n0 = 16 * w;
  short8 a0 = *(const short8*)(&Bwt[n0 + l15][lq * 8]);
  short8 a1 = *(const short8*)(&Bwt[n0 + l15][32 + lq * 8]);
  size_t sb = ((size_t)bh * 64 + c) * 4096;
  #pragma unroll
  for (int pt = 0; pt < 4; pt++) {
    f32x4 acc = (f32x4){0.f, 0.f, 0.f, 0.f};
    short8 b0 = *(const short8*)(&Xt[16*pt + l15][lq * 8]);
    short8 b1 = *(const short8*)(&Xt[16*pt + l15][32 + lq * 8]);
    acc = __builtin_amdgcn_mfma_f32_16x16x32_bf16(a0, b0, acc, 0, 0, 0);
    acc = __builtin_amdgcn_mfma_f32_16x16x32_bf16(a1, b1, acc, 0, 0, 0);
    #pragma unroll
    for (int r = 0; r < 4; r++) {
      int n = n0 + 4*lq + r, p = 16*pt + l15;
      S[sb + (size_t)n * 64 + p] = f2bf(acc[r]);
    }
  }
}

// ---------------- SSD pass 2: chunk recurrence (bf16 S, fp32 reg accumulator) ----
__global__ __launch_bounds__(256) void k_chunkrec(unsigned short* __restrict__ S,
    const float* __restrict__ CD)
{
  const int bh = blockIdx.x >> 4, part = blockIdx.x & 15;
  const int e = part * 256 + threadIdx.x;
  float g = 0.f;
  size_t base = (size_t)bh * 64 * 4096 + e;
  for (int c = 0; c < 64; c++) {
    size_t ad = base + (size_t)c * 4096;
    float sv = bf2f(S[ad]);
    float pc = CD[bh * 64 + c];
    S[ad] = f2bf(g);         // slot c now holds G_c (state before chunk c)
    g = pc * g + sv;
  }
}

// ---------------- SSD pass 3 (MFMA): per-chunk outputs (bf16 Y out) --------------
__global__ __launch_bounds__(256) void k_chunkout(const unsigned short* __restrict__ zx,
    const unsigned short* __restrict__ xbcc, const unsigned short* __restrict__ S,
    const float* __restrict__ dt_bias, const float* __restrict__ A_log,
    const float* __restrict__ Dp, unsigned short* __restrict__ Y)
{
  const int c = blockIdx.x, bh = blockIdx.y;
  const int b = bh / NH, h = bh % NH;
  const int tid = threadIdx.x;
  const int lane = tid & 63, w = tid >> 6;
  const int l15 = lane & 15, lq = lane >> 4;
  __shared__ float dts[64], Lc[64], ein[64];
  __shared__ alignas(16) unsigned short Cs  [64][LP];  // [i][n]
  __shared__ alignas(16) unsigned short BsPs[64][LP];  // [s][n], then P[i][s]
  __shared__ alignas(16) unsigned short Xt  [64][LP];  // [p][s]
  __shared__ alignas(16) unsigned short Gt  [64][LP];  // [p][n]

  if (tid < 64) {                     // wave 0: dt, prefix-scan of Lc
    int t = c * 64 + tid;
    float xx = bf2f(zx[((size_t)(b * SEQ + t)) * DINPROJ + (DINNER + CONVD) + h]) + dt_bias[h];
    float dt_ = (xx > 15.f) ? xx : log1pf(__expf(xx));
    dts[tid] = dt_;
    float Ah = -__expf(A_log[h]);
    float v = dt_ * Ah;
    #pragma unroll
    for (int off = 1; off < 64; off <<= 1) {
      float u = __shfl_up(v, off);
      if (tid >= off) v += u;
    }
    Lc[tid] = v;
    ein[tid] = __expf(v);
  }
  const size_t gslot = ((size_t)bh * 64 + c) * 4096;
  #pragma unroll
  for (int it = 0; it < 4; it++) {
    int i4 = tid + 256 * it;
    int rr = i4 >> 4, q4 = (i4 & 15) * 4;
    size_t rb = ((size_t)(b * SEQ) + c * 64 + rr) * CONVD;
    const unsigned short* pC = xbcc + rb + (DINNER + DSTATE) + q4;
    Cs[rr][q4+0] = pC[0]; Cs[rr][q4+1] = pC[1]; Cs[rr][q4+2] = pC[2]; Cs[rr][q4+3] = pC[3];
    const unsigned short* pB = xbcc + rb + DINNER + q4;
    BsPs[rr][q4+0] = pB[0]; BsPs[rr][q4+1] = pB[1]; BsPs[rr][q4+2] = pB[2]; BsPs[rr][q4+3] = pB[3];
    unsigned short xs[4];
    *(unsigned long long*)xs = *(const unsigned long long*)(xbcc + rb + h * HD + q4);
    Xt[q4+0][rr] = xs[0]; Xt[q4+1][rr] = xs[1]; Xt[q4+2][rr] = xs[2]; Xt[q4+3][rr] = xs[3];
    unsigned short gs[4];
    *(unsigned long long*)gs = *(const unsigned long long*)(S + gslot + (size_t)i4 * 4);
    Gt[q4+0][rr] = gs[0]; Gt[q4+1][rr] = gs[1]; Gt[q4+2][rr] = gs[2]; Gt[q4+3][rr] = gs[3];
  }
  __syncthreads();
  // ---- matmul1: G[i][s] = sum_n C[i][n] B[s][n]; apply causal decay mask -> P ----
  const int i0 = 16 * w;
  short8 ac0 = *(const short8*)(&Cs[i0 + l15][lq * 8]);
  short8 ac1 = *(const short8*)(&Cs[i0 + l15][32 + lq * 8]);
  float pp[4][4];
  #pragma unroll
  for (int st = 0; st < 4; st++) {
    f32x4 g = (f32x4){0.f, 0.f, 0.f, 0.f};
    if (st <= w) {                                   // wave-uniform causal skip
      short8 b0 = *(const short8*)(&BsPs[16*st + l15][lq * 8]);
      short8 b1 = *(const short8*)(&BsPs[16*st + l15][32 + lq * 8]);
      g = __builtin_amdgcn_mfma_f32_16x16x32_bf16(ac0, b0, g, 0, 0, 0);
      g = __builtin_amdgcn_mfma_f32_16x16x32_bf16(ac1, b1, g, 0, 0, 0);
    }
    #pragma unroll
    for (int r = 0; r < 4; r++) {
      int i = i0 + 4*lq + r, s = 16*st + l15;
      pp[st][r] = (s <= i) ? g[r] * __expf(Lc[i] - Lc[s]) * dts[s] : 0.f;
    }
  }
  __syncthreads();                                   // all waves done reading Bs
  #pragma unroll
  for (int st = 0; st < 4; st++)
    #pragma unroll
    for (int r = 0; r < 4; r++)
      BsPs[i0 + 4*lq + r][16*st + l15] = f2bf(pp[st][r]);   // P[i][s], s contiguous
  __syncthreads();
  // ---- matmul2+3: Y[i][p] = P@X + ein[i]*(C@G) + D*x ----
  short8 ap0 = *(const short8*)(&BsPs[i0 + l15][lq * 8]);
  short8 ap1 = *(const short8*)(&BsPs[i0 + l15][32 + lq * 8]);
  const float Dh = Dp[h];
  #pragma unroll
  for (int pt = 0; pt < 4; pt++) {
    const int p0 = 16 * pt;
    f32x4 y1 = (f32x4){0.f, 0.f, 0.f, 0.f};
    f32x4 y2 = (f32x4){0.f, 0.f, 0.f, 0.f};
    short8 bx0 = *(const short8*)(&Xt[p0 + l15][lq * 8]);
    y1 = __builtin_amdgcn_mfma_f32_16x16x32_bf16(ap0, bx0, y1, 0, 0, 0);
    if (w >= 2) {                                    // P rows of wave w have k < 16(w+1)
      short8 bx1 = *(const short8*)(&Xt[p0 + l15][32 + lq * 8]);
      y1 = __builtin_amdgcn_mfma_f32_16x16x32_bf16(ap1, bx1, y1, 0, 0, 0);
    }
    short8 bg0 = *(const short8*)(&Gt[p0 + l15][lq * 8]);
    short8 bg1 = *(const short8*)(&Gt[p0 + l15][32 + lq * 8]);
    y2 = __builtin_amdgcn_mfma_f32_16x16x32_bf16(ac0, bg0, y2, 0, 0, 0);
    y2 = __builtin_amdgcn_mfma_f32_16x16x32_bf16(ac1, bg1, y2, 0, 0, 0);
    #pragma unroll
    for (int r = 0; r < 4; r++) {
      int i = i0 + 4*lq + r, p = p0 + l15;
      float xv = bf2f(Xt[p][i]);
      float o = y1[r] + ein[i] * y2[r] + Dh * xv;
      Y[((size_t)(b * SEQ) + c * 64 + i) * DINNER + h * HD + p] = f2bf(o);
    }
  }
}

// ---------------- y*silu(z), RMSNorm -> bf16 -------------------------------------
__global__ __launch_bounds__(256) void k_fuse(const unsigned short* __restrict__ Y,
    const unsigned short* __restrict__ ZX, const float* __restrict__ rw,
    unsigned short* __restrict__ YN)
{
  __shared__ float red[4];
  const int row = blockIdx.x, tid = threadIdx.x;
  const unsigned short* yr = Y + (size_t)row * DINNER;
  const unsigned short* zr = ZX + (size_t)row * DINPROJ;
  float v[6]; float s2 = 0.f;
  #pragma unroll
  for (int q = 0; q < 6; q++) {
    int col = q * 256 + tid;
    float z = bf2f(zr[col]);
    float yv = bf2f(yr[col]) * (z * sigm(z));
    v[q] = yv; s2 += yv * yv;
  }
  #pragma unroll
  for (int off = 32; off; off >>= 1) s2 += __shfl_down(s2, off);
  if ((tid & 63) == 0) red[tid >> 6] = s2;
  __syncthreads();
  const float rs = rsqrtf((red[0] + red[1] + red[2] + red[3]) * (1.f / DINNER) + EPSF);
  unsigned short* yo = YN + (size_t)row * DINNER;
  #pragma unroll
  for (int q = 0; q < 6; q++) {
    int col = q * 256 + tid;
    yo[col] = f2bf(v[q] * rs * rw[col]);
  }
}

// ---------------- yg = bf16(yproj * gate), 4 elems/thread ------------------------
__global__ __launch_bounds__(256) void k_gatemul(const unsigned short* __restrict__ YP,
    const unsigned short* __restrict__ G, unsigned short* __restrict__ YG)
{
  size_t i4 = ((size_t)blockIdx.x * 256 + threadIdx.x) * 4;
  unsigned short a[4], b[4];
  *(unsigned long long*)a = *(const unsigned long long*)(YP + i4);
  *(unsigned long long*)b = *(const unsigned long long*)(G + i4);
  *(unsigned long long*)(YG + i4) = pack4bf(
      bf2f(a[0]) * bf2f(b[0]), bf2f(a[1]) * bf2f(b[1]),
      bf2f(a[2]) * bf2f(b[2]), bf2f(a[3]) * bf2f(b[3]));
}

// ---------------- launch ----------------------------------------------------------
extern "C" void kernel_launch(void* const* d_in, const int* in_sizes, int n_in,
                              void* d_out, int out_size, void* d_ws, size_t ws_size,
                              hipStream_t stream)
{
  const float* x         = (const float*)d_in[0];
  const float* ln_w      = (const float*)d_in[1];
  const float* ln_b      = (const float*)d_in[2];
  const float* in_proj_w = (const float*)d_in[3];
  const float* conv_w    = (const float*)d_in[4];
  const float* conv_b    = (const float*)d_in[5];
  const float* dt_bias   = (const float*)d_in[6];
  const float* A_log     = (const float*)d_in[7];
  const float* D_param   = (const float*)d_in[8];
  const float* rms_w     = (const float*)d_in[9];
  const float* out_proj_w= (const float*)d_in[10];
  const float* gate_w    = (const float*)d_in[11];
  const float* gate_b    = (const float*)d_in[12];
  const float* out_w     = (const float*)d_in[13];
  const float* out_b     = (const float*)d_in[14];
  float* out = (float*)d_out;
  char* ws = (char*)d_ws;

  // ---- workspace layout (bytes). peak = 177,848,320 B (~170 MB) ----
  // S is bf16 now (25.2 MB at 102338560..127504384); Gb lives at 127504384
  // (inside the old fp32-S span, after bf16-S ends); YN overlays 102338560
  // (dead S) and ends exactly at Gb. All lifetimes re-checked.
  const size_t WS_NEEDED = 177848320ull;
  if (ws_size < WS_NEEDED) return;

  unsigned short* XN    = (unsigned short*)(ws + 0);
  unsigned short* WIT   = (unsigned short*)(ws + 12582912);
  unsigned short* WGT   = (unsigned short*)(ws + 17534976);
  unsigned short* WOPT  = (unsigned short*)(ws + 18714624);
  unsigned short* WOT   = (unsigned short*)(ws + 21073920);
  unsigned short* ZXb   = (unsigned short*)(ws + 22253568);   // 8192x3224 bf16
  unsigned short* XBCCb = (unsigned short*)(ws + 75075584);   // 8192x1664 bf16
  unsigned short* Sb    = (unsigned short*)(ws + 102338560);  // 3072x4096 bf16 (25.2MB)
  unsigned short* Gb    = (unsigned short*)(ws + 127504384);  // 8192x768 bf16 (gate out)
  float*          CD    = (float*)(ws + 152670208);           // 3072 f32
  unsigned short* Yb    = (unsigned short*)(ws + 152682496);  // 8192x1536 bf16
  // overlays:
  unsigned short* YN    = (unsigned short*)(ws + 102338560);  // in dead-S region, ends at Gb
  unsigned short* YPb   = (unsigned short*)(ws + 34836480);   // in ZXb region (dead after fuse)
  unsigned short* YG    = (unsigned short*)(ws + 75075584);   // in XBCCb region (dead after chunkout)

  // 1) weight converts, single dispatch
  k_wtrans4<<<dim3(101, 48, 4), 256, 0, stream>>>(in_proj_w, WIT, gate_w, WGT,
                                                  out_proj_w, WOPT, out_w, WOT);
  // 2) layernorm
  k_ln<<<NTOK, 256, 0, stream>>>(x, ln_w, ln_b, XN);
  // 3) in_proj + gate GEMMs, one dispatch (2048 blocks = 4 exact rounds)
  k_ipg<<<2048, 256, 0, stream>>>(XN, WIT, ZXb, WGT, Gb, gate_b);
  // 4) LDS-tiled causal conv + silu (bf16 -> bf16)
  k_conv<<<dim3(13, 128), 256, 0, stream>>>(ZXb, conv_w, conv_b, XBCCb);
  // 5-7) SSD scan (S in bf16)
  k_chunkstate<<<dim3(NCHUNK, BSZ * NH), 256, 0, stream>>>(ZXb, XBCCb, dt_bias, A_log, Sb, CD);
  k_chunkrec<<<BSZ * NH * 16, 256, 0, stream>>>(Sb, CD);
  k_chunkout<<<dim3(NCHUNK, BSZ * NH), 256, 0, stream>>>(ZXb, XBCCb, Sb, dt_bias, A_log, D_param, Yb);
  // 8) y*silu(z) + RMSNorm -> bf16 (YN lands in dead-S region)
  k_fuse<<<NTOK, 256, 0, stream>>>(Yb, ZXb, rms_w, YN);
  // 9) out_proj GEMM -> YPb (bf16)
  k_gemm<<<dim3(6, 64), 256, 0, stream>>>(YN, WOPT, nullptr, YPb, NTOK, DMODEL, DINNER, 0, nullptr, nullptr);
  // 10) gate multiply -> bf16
  k_gatemul<<<(NTOK * DMODEL / 4) / 256, 256, 0, stream>>>(YPb, Gb, YG);
  // 11) final GEMM + bias + residual -> d_out
  k_gemm<<<dim3(6, 64), 256, 0, stream>>>(YG, WOT, out, nullptr, NTOK, DMODEL, DMODEL, 2, out_b, x);
}